// Round 1
// baseline (2986.550 us; speedup 1.0000x reference)
//
#include <hip/hip_runtime.h>
#include <stdint.h>

#define B_IMG 64
#define NIMG 128
#define NS 576
#define NT 1024
#define DSZ 1024
#define DT 1152
#define SH_ 24
#define SW_ 24
#define TH_ 32
#define TW_ 32
#define TEMPR 0.02f
#define EPS_ 1e-6f

typedef float f32x4 __attribute__((ext_vector_type(4)));
typedef __bf16 bf16x8 __attribute__((ext_vector_type(8)));

// ---------- ws layout ----------
constexpr size_t SZ_PROJ = (size_t)NIMG * NT * DSZ * 2;     // bf16 proj
constexpr size_t OFF_PROJ = 0;
constexpr size_t OFF_WT = OFF_PROJ + SZ_PROJ;               // bf16 W^T [DSZ][DT]
constexpr size_t SZ_WT = (size_t)DSZ * DT * 2;
constexpr size_t OFF_NORMP = OFF_WT + SZ_WT;                // f32 [NIMG*NT]
constexpr size_t OFF_NORMS = OFF_NORMP + (size_t)NIMG * NT * 4;   // f32 [NIMG*NS]
constexpr size_t OFF_C2MIN = OFF_NORMS + (size_t)NIMG * NS * 4;   // i32 [NIMG]
constexpr size_t OFF_C2MAX = OFF_C2MIN + NIMG * 4;
constexpr size_t OFF_C1MM = OFF_C2MAX + NIMG * 4;           // 2 x i32
constexpr size_t OFF_ACC = OFF_C1MM + 16;                   // 2 x f32 (contr, kd)
constexpr size_t OFF_ARG = OFF_ACC + 16;                    // u64 [NIMG*NS]
constexpr size_t SZ_ARG = (size_t)NIMG * NS * 8;
constexpr size_t WS_NEEDED = OFF_ARG + SZ_ARG;

// ---------- helpers ----------
__device__ __forceinline__ unsigned short f2bf(float f) {
  union { float f; uint32_t u; } c; c.f = f;
  uint32_t u = c.u;
  uint32_t r = u + 0x7FFFu + ((u >> 16) & 1u);
  return (unsigned short)(r >> 16);
}
__device__ __forceinline__ float bf2f(unsigned short b) {
  union { float f; uint32_t u; } c; c.u = ((uint32_t)b) << 16;
  return c.f;
}
__device__ __forceinline__ float c1raw(int i, int j) {
  float ys = ((float)(i / SW_) + 0.5f) / (float)SH_ * 2.0f - 1.0f;
  float xs = ((float)(i % SW_) + 0.5f) / (float)SW_ * 2.0f - 1.0f;
  float yt = ((float)(j / TW_) + 0.5f) / (float)TH_ * 2.0f - 1.0f;
  float xt = ((float)(j % TW_) + 0.5f) / (float)TW_ * 2.0f - 1.0f;
  return fabsf(ys - yt) + fabsf(xs - xt);
}
__device__ __forceinline__ float blockRedSum(float v) {
  #pragma unroll
  for (int o = 32; o; o >>= 1) v += __shfl_xor(v, o);
  __shared__ float red[4];
  int w = threadIdx.x >> 6;
  if ((threadIdx.x & 63) == 0) red[w] = v;
  __syncthreads();
  float tot = 0.f;
  if (threadIdx.x == 0) {
    int nw = blockDim.x >> 6;
    for (int i = 0; i < nw; i++) tot += red[i];
  }
  return tot;
}

// ---------- kernels ----------
__global__ __launch_bounds__(256) void initK(unsigned long long* argw, int* c2mn,
                                             int* c2mx, int* c1mm, float* accf) {
  int i = blockIdx.x * 256 + threadIdx.x;
  if (i < NIMG * NS) argw[i] = ~0ull;
  if (i < NIMG) { c2mn[i] = 0x7F800000; c2mx[i] = 0; }
  if (i == 0) { c1mm[0] = 0x7F800000; c1mm[1] = 0; accf[0] = 0.f; accf[1] = 0.f; }
}

__global__ __launch_bounds__(256) void wtK(const float* __restrict__ W,
                                           unsigned short* __restrict__ Wt) {
  int i = blockIdx.x * 256 + threadIdx.x;  // over DSZ*DT
  int n = i / DT, k = i % DT;
  Wt[i] = f2bf(W[(size_t)k * DSZ + n]);
}

__global__ __launch_bounds__(256) void c1K(int* c1mm) {
  int tid = blockIdx.x * 256 + threadIdx.x;
  float lmin = __builtin_inff(), lmax = 0.f;
  for (int p = tid; p < NS * NT; p += gridDim.x * 256) {
    float v = c1raw(p / NT, p % NT);
    lmin = fminf(lmin, v);
    lmax = fmaxf(lmax, v);
  }
  #pragma unroll
  for (int o = 32; o; o >>= 1) {
    lmin = fminf(lmin, __shfl_xor(lmin, o));
    lmax = fmaxf(lmax, __shfl_xor(lmax, o));
  }
  if ((threadIdx.x & 63) == 0) {
    atomicMin(c1mm, __float_as_int(lmin));
    atomicMax(c1mm + 1, __float_as_int(lmax));
  }
}

__global__ __launch_bounds__(64) void contrK(const float* __restrict__ q,
                                             const float* __restrict__ p,
                                             float* accf) {
  int i = blockIdx.x, l = threadIdx.x;
  const float4* qi = (const float4*)(q + (size_t)i * DSZ);
  const float4* pj = (const float4*)(p + (size_t)l * DSZ);
  float dot = 0.f;
  for (int k = 0; k < DSZ / 4; k++) {
    float4 a = qi[k], b = pj[k];
    dot += a.x * b.x + a.y * b.y + a.z * b.z + a.w * b.w;
  }
  float s = dot / TEMPR;
  float m = s;
  #pragma unroll
  for (int o = 32; o; o >>= 1) m = fmaxf(m, __shfl_xor(m, o));
  float e = expf(s - m);
  #pragma unroll
  for (int o = 32; o; o >>= 1) e += __shfl_xor(e, o);
  float lse = m + logf(e);
  float sii = __shfl(s, i);
  if (l == 0) atomicAdd(accf, sii - lse);
}

__global__ __launch_bounds__(256) void normsK(const float* __restrict__ sq,
                                              const float* __restrict__ sp,
                                              float* __restrict__ normS) {
  int r = blockIdx.x;
  int b = r / NS, i = r % NS;
  const float* row = (b < B_IMG) ? sq + ((size_t)b * NS + i) * DSZ
                                 : sp + ((size_t)(b - B_IMG) * NS + i) * DSZ;
  float4 v = ((const float4*)row)[threadIdx.x];
  float s = v.x * v.x + v.y * v.y + v.z * v.z + v.w * v.w;
  float tot = blockRedSum(s);
  if (threadIdx.x == 0) normS[r] = tot;
}

__global__ __launch_bounds__(128) void normpK(const unsigned short* __restrict__ proj,
                                              float* __restrict__ normP) {
  int r = blockIdx.x;
  const uint4 u = ((const uint4*)(proj + (size_t)r * DSZ))[threadIdx.x];
  float s = 0.f;
  uint32_t vv[4] = {u.x, u.y, u.z, u.w};
  #pragma unroll
  for (int k = 0; k < 4; k++) {
    float lo = bf2f((unsigned short)(vv[k] & 0xFFFF));
    float hi = bf2f((unsigned short)(vv[k] >> 16));
    s += lo * lo + hi * hi;
  }
  #pragma unroll
  for (int o = 32; o; o >>= 1) s += __shfl_xor(s, o);
  __shared__ float red[2];
  if ((threadIdx.x & 63) == 0) red[threadIdx.x >> 6] = s;
  __syncthreads();
  if (threadIdx.x == 0) normP[r] = red[0] + red[1];
}

// MODE 0: proj = tea @ W^T^T + b   (M=NT, K=DT, N=DSZ), store bf16 proj
// MODE 1: G = stu @ proj^T, track per-image c2 min/max
// MODE 2: same G, per-row argmin of c1n + 1e-3*c2n
template <int MODE>
__global__ __launch_bounds__(256) void gemmK(
    const float* __restrict__ teaQ, const float* __restrict__ teaP,
    const unsigned short* __restrict__ Wt, const float* __restrict__ bias,
    unsigned short* __restrict__ proj, const float* __restrict__ stuQ,
    const float* __restrict__ stuP, const float* __restrict__ normS,
    const float* __restrict__ normP, int* __restrict__ c2mn,
    int* __restrict__ c2mx, const int* __restrict__ c1mm,
    unsigned long long* __restrict__ argw) {
  constexpr int K = (MODE == 0) ? DT : DSZ;
  constexpr int MR = (MODE == 0) ? NT : NS;
  const int b = blockIdx.y;
  const int mt = blockIdx.x >> 3;
  const int nt = blockIdx.x & 7;
  const int M0 = mt * 128, N0 = nt * 128;

  const float* Af32;
  const unsigned short* Bbf;
  if (MODE == 0) {
    Af32 = (b < B_IMG) ? teaQ + (size_t)b * NT * DT
                       : teaP + (size_t)(b - B_IMG) * NT * DT;
    Bbf = Wt;
  } else {
    Af32 = (b < B_IMG) ? stuQ + (size_t)b * NS * DSZ
                       : stuP + (size_t)(b - B_IMG) * NS * DSZ;
    Bbf = proj + (size_t)b * NT * DSZ;
  }

  __shared__ unsigned short As[128 * 32];
  __shared__ unsigned short Bs[128 * 32];

  const int t = threadIdx.x;
  const int l = t & 63;
  const int wid = t >> 6;
  const int wr = wid >> 1, wc = wid & 1;

  f32x4 acc[4][4];
  #pragma unroll
  for (int i = 0; i < 4; i++)
    #pragma unroll
    for (int j = 0; j < 4; j++) acc[i][j] = (f32x4){0.f, 0.f, 0.f, 0.f};

  const int arow = t >> 1;
  const int akh = (t & 1) * 16;
  int garow = M0 + arow;
  if (MODE != 0) garow = min(garow, MR - 1);
  const float* aptr = Af32 + (size_t)garow * K + akh;
  const unsigned short* bptr = Bbf + (size_t)(N0 + arow) * K + akh;

  for (int kt = 0; kt < K; kt += 32) {
    const float4* a4 = (const float4*)(aptr + kt);
    float4 x0 = a4[0], x1 = a4[1], x2 = a4[2], x3 = a4[3];
    uint4 c0, c1v;
    c0.x = (uint32_t)f2bf(x0.x) | ((uint32_t)f2bf(x0.y) << 16);
    c0.y = (uint32_t)f2bf(x0.z) | ((uint32_t)f2bf(x0.w) << 16);
    c0.z = (uint32_t)f2bf(x1.x) | ((uint32_t)f2bf(x1.y) << 16);
    c0.w = (uint32_t)f2bf(x1.z) | ((uint32_t)f2bf(x1.w) << 16);
    c1v.x = (uint32_t)f2bf(x2.x) | ((uint32_t)f2bf(x2.y) << 16);
    c1v.y = (uint32_t)f2bf(x2.z) | ((uint32_t)f2bf(x2.w) << 16);
    c1v.z = (uint32_t)f2bf(x3.x) | ((uint32_t)f2bf(x3.y) << 16);
    c1v.w = (uint32_t)f2bf(x3.z) | ((uint32_t)f2bf(x3.w) << 16);
    *(uint4*)&As[arow * 32 + akh] = c0;
    *(uint4*)&As[arow * 32 + akh + 8] = c1v;
    const uint4* b4 = (const uint4*)(bptr + kt);
    *(uint4*)&Bs[arow * 32 + akh] = b4[0];
    *(uint4*)&Bs[arow * 32 + akh + 8] = b4[1];
    __syncthreads();

    bf16x8 af[4], bfv[4];
    #pragma unroll
    for (int mi = 0; mi < 4; mi++)
      af[mi] = *(const bf16x8*)&As[(wr * 64 + mi * 16 + (l & 15)) * 32 + (l >> 4) * 8];
    #pragma unroll
    for (int ni = 0; ni < 4; ni++)
      bfv[ni] = *(const bf16x8*)&Bs[(wc * 64 + ni * 16 + (l & 15)) * 32 + (l >> 4) * 8];
    #pragma unroll
    for (int mi = 0; mi < 4; mi++)
      #pragma unroll
      for (int ni = 0; ni < 4; ni++)
        acc[mi][ni] =
            __builtin_amdgcn_mfma_f32_16x16x32_bf16(af[mi], bfv[ni], acc[mi][ni], 0, 0, 0);
    __syncthreads();
  }

  const int rbase = (l >> 4) * 4;
  const int cl = l & 15;

  if (MODE == 0) {
    #pragma unroll
    for (int mi = 0; mi < 4; mi++) {
      int row = M0 + wr * 64 + mi * 16 + rbase;
      #pragma unroll
      for (int ni = 0; ni < 4; ni++) {
        int col = N0 + wc * 64 + ni * 16 + cl;
        float bv = bias[col];
        #pragma unroll
        for (int r = 0; r < 4; r++) {
          float v = acc[mi][ni][r] + bv;
          proj[((size_t)b * NT + row + r) * DSZ + col] = f2bf(v);
        }
      }
    }
  } else if (MODE == 1) {
    float lmin = __builtin_inff(), lmax = -1.f;
    #pragma unroll
    for (int mi = 0; mi < 4; mi++) {
      #pragma unroll
      for (int r = 0; r < 4; r++) {
        int row = M0 + wr * 64 + mi * 16 + rbase + r;
        if (row < NS) {
          float ns = normS[b * NS + row];
          #pragma unroll
          for (int ni = 0; ni < 4; ni++) {
            int col = N0 + wc * 64 + ni * 16 + cl;
            float sq = ns + normP[b * NT + col] - 2.f * acc[mi][ni][r];
            float c2 = sqrtf(fmaxf(sq, 0.f));
            lmin = fminf(lmin, c2);
            lmax = fmaxf(lmax, c2);
          }
        }
      }
    }
    #pragma unroll
    for (int o = 32; o; o >>= 1) {
      lmin = fminf(lmin, __shfl_xor(lmin, o));
      lmax = fmaxf(lmax, __shfl_xor(lmax, o));
    }
    if (l == 0) {
      atomicMin(&c2mn[b], __float_as_int(lmin));
      atomicMax(&c2mx[b], __float_as_int(lmax));
    }
  } else {
    float c1mn = __int_as_float(c1mm[0]);
    float c1mx = __int_as_float(c1mm[1]);
    float c1s = 1.f / (c1mx - c1mn + EPS_);
    float c2mnv = __int_as_float(c2mn[b]);
    float c2mxv = __int_as_float(c2mx[b]);
    float c2s = 1e-3f / (c2mxv - c2mnv + EPS_);
    #pragma unroll
    for (int mi = 0; mi < 4; mi++) {
      #pragma unroll
      for (int r = 0; r < 4; r++) {
        int row = M0 + wr * 64 + mi * 16 + rbase + r;
        unsigned long long key = ~0ull;
        if (row < NS) {
          float ns = normS[b * NS + row];
          #pragma unroll
          for (int ni = 0; ni < 4; ni++) {
            int col = N0 + wc * 64 + ni * 16 + cl;
            float sq = ns + normP[b * NT + col] - 2.f * acc[mi][ni][r];
            float c2 = sqrtf(fmaxf(sq, 0.f));
            float val = (c1raw(row, col) - c1mn) * c1s + (c2 - c2mnv) * c2s;
            unsigned long long k2 =
                ((unsigned long long)(uint32_t)__float_as_int(val) << 32) | (uint32_t)col;
            key = (k2 < key) ? k2 : key;
          }
        }
        #pragma unroll
        for (int o = 1; o < 16; o <<= 1) {
          unsigned long long other = __shfl_xor(key, o);
          key = (other < key) ? other : key;
        }
        if (cl == 0 && row < NS) atomicMin(&argw[(size_t)b * NS + row], key);
      }
    }
  }
}

__global__ __launch_bounds__(256) void mseK(const float* __restrict__ stuQ,
                                            const float* __restrict__ stuP,
                                            const unsigned short* __restrict__ proj,
                                            const unsigned long long* __restrict__ argw,
                                            float* accf) {
  int rr = blockIdx.x;
  int b = rr / NS, i = rr % NS;
  const float* srow = (b < B_IMG) ? stuQ + ((size_t)b * NS + i) * DSZ
                                  : stuP + ((size_t)(b - B_IMG) * NS + i) * DSZ;
  int idx = (int)(argw[rr] & 0xFFFFFFFFull);
  const unsigned short* prow = proj + ((size_t)b * NT + idx) * DSZ;
  float4 s = ((const float4*)srow)[threadIdx.x];
  ushort4 p = ((const ushort4*)prow)[threadIdx.x];
  float d0 = s.x - bf2f(p.x);
  float d1 = s.y - bf2f(p.y);
  float d2 = s.z - bf2f(p.z);
  float d3 = s.w - bf2f(p.w);
  float tot = blockRedSum(d0 * d0 + d1 * d1 + d2 * d2 + d3 * d3);
  if (threadIdx.x == 0) atomicAdd(accf + 1, tot);
}

__global__ void finalK(const float* accf, float* out) {
  float contr = -accf[0] / (float)B_IMG;
  float kd = (accf[1] / (float)(NS * DSZ)) / (2.f * B_IMG + 1e-8f);
  out[0] = contr + kd;
}

extern "C" void kernel_launch(void* const* d_in, const int* in_sizes, int n_in,
                              void* d_out, int out_size, void* d_ws, size_t ws_size,
                              hipStream_t stream) {
  const float* stuQ = (const float*)d_in[0];
  const float* teaQ = (const float*)d_in[1];
  const float* stuP = (const float*)d_in[2];
  const float* teaP = (const float*)d_in[3];
  const float* qreps = (const float*)d_in[4];
  const float* preps = (const float*)d_in[5];
  const float* W = (const float*)d_in[6];
  const float* bias = (const float*)d_in[7];

  if (ws_size < WS_NEEDED) return;  // insufficient scratch — cannot compute

  char* ws = (char*)d_ws;
  unsigned short* proj = (unsigned short*)(ws + OFF_PROJ);
  unsigned short* Wt = (unsigned short*)(ws + OFF_WT);
  float* normP = (float*)(ws + OFF_NORMP);
  float* normS = (float*)(ws + OFF_NORMS);
  int* c2mn = (int*)(ws + OFF_C2MIN);
  int* c2mx = (int*)(ws + OFF_C2MAX);
  int* c1mm = (int*)(ws + OFF_C1MM);
  float* accf = (float*)(ws + OFF_ACC);
  unsigned long long* argw = (unsigned long long*)(ws + OFF_ARG);
  float* out = (float*)d_out;

  initK<<<dim3((NIMG * NS + 255) / 256), dim3(256), 0, stream>>>(argw, c2mn, c2mx, c1mm, accf);
  wtK<<<dim3(DSZ * DT / 256), dim3(256), 0, stream>>>(W, Wt);
  c1K<<<dim3(64), dim3(256), 0, stream>>>(c1mm);
  contrK<<<dim3(B_IMG), dim3(64), 0, stream>>>(qreps, preps, accf);
  normsK<<<dim3(NIMG * NS), dim3(256), 0, stream>>>(stuQ, stuP, normS);
  gemmK<0><<<dim3(64, NIMG), dim3(256), 0, stream>>>(teaQ, teaP, Wt, bias, proj, stuQ,
                                                     stuP, normS, normP, c2mn, c2mx, c1mm, argw);
  normpK<<<dim3(NIMG * NT), dim3(128), 0, stream>>>(proj, normP);
  gemmK<1><<<dim3(40, NIMG), dim3(256), 0, stream>>>(teaQ, teaP, Wt, bias, proj, stuQ,
                                                     stuP, normS, normP, c2mn, c2mx, c1mm, argw);
  gemmK<2><<<dim3(40, NIMG), dim3(256), 0, stream>>>(teaQ, teaP, Wt, bias, proj, stuQ,
                                                     stuP, normS, normP, c2mn, c2mx, c1mm, argw);
  mseK<<<dim3(NIMG * NS), dim3(256), 0, stream>>>(stuQ, stuP, proj, argw, accf);
  finalK<<<dim3(1), dim3(1), 0, stream>>>(accf, out);
}

// Round 2
// 2375.621 us; speedup vs baseline: 1.2572x; 1.2572x over previous
//
#include <hip/hip_runtime.h>
#include <stdint.h>

#define B_IMG 64
#define NIMG 128
#define NS 576
#define NT 1024
#define DSZ 1024
#define DT 1152
#define SH_ 24
#define SW_ 24
#define TH_ 32
#define TW_ 32
#define TEMPR 0.02f
#define EPS_ 1e-6f

typedef float f32x4 __attribute__((ext_vector_type(4)));
typedef __bf16 bf16x8 __attribute__((ext_vector_type(8)));

// ---------- ws layout ----------
// base section (always needed)
constexpr size_t OFF_PROJ = 0;                                   // bf16 proj [NIMG][NT][DSZ]
constexpr size_t SZ_PROJ = (size_t)NIMG * NT * DSZ * 2;
constexpr size_t OFF_WT = OFF_PROJ + SZ_PROJ;                    // bf16 W^T [DSZ][DT]
constexpr size_t SZ_WT = (size_t)DSZ * DT * 2;
constexpr size_t OFF_NORMP = OFF_WT + SZ_WT;                     // f32 [NIMG*NT]
constexpr size_t OFF_NORMS = OFF_NORMP + (size_t)NIMG * NT * 4;  // f32 [NIMG*NS]
constexpr size_t OFF_C2MIN = OFF_NORMS + (size_t)NIMG * NS * 4;
constexpr size_t OFF_C2MAX = OFF_C2MIN + NIMG * 4;
constexpr size_t OFF_C1MM = OFF_C2MAX + NIMG * 4;                // 2 x i32
constexpr size_t OFF_ACC = OFF_C1MM + 16;                        // 2 x f32
constexpr size_t OFF_ARG = OFF_ACC + 16;                         // u64 [NIMG*NS]
constexpr size_t SZ_ARG = (size_t)NIMG * NS * 8;
constexpr size_t WS_BASIC = OFF_ARG + SZ_ARG;
// extended section (bf16 copies of A operands)
constexpr size_t OFF_TEA = (WS_BASIC + 255) & ~(size_t)255;      // bf16 [NIMG][NT][DT]
constexpr size_t SZ_TEA = (size_t)NIMG * NT * DT * 2;
constexpr size_t OFF_STU = OFF_TEA + SZ_TEA;                     // bf16 [NIMG][NS][DSZ] + pad
constexpr size_t SZ_STU = (size_t)NIMG * NS * DSZ * 2 + 64 * DSZ * 2;  // pad 64 rows
constexpr size_t WS_FULL = OFF_STU + SZ_STU;

// ---------- helpers ----------
__device__ __forceinline__ unsigned short f2bf(float f) {
  union { float f; uint32_t u; } c; c.f = f;
  uint32_t u = c.u;
  uint32_t r = u + 0x7FFFu + ((u >> 16) & 1u);
  return (unsigned short)(r >> 16);
}
__device__ __forceinline__ float bf2f(unsigned short b) {
  union { float f; uint32_t u; } c; c.u = ((uint32_t)b) << 16;
  return c.f;
}
__device__ __forceinline__ bf16x8 cvt8(float4 a, float4 b) {
  bf16x8 r;
  r[0] = (__bf16)a.x; r[1] = (__bf16)a.y; r[2] = (__bf16)a.z; r[3] = (__bf16)a.w;
  r[4] = (__bf16)b.x; r[5] = (__bf16)b.y; r[6] = (__bf16)b.z; r[7] = (__bf16)b.w;
  return r;
}
__device__ __forceinline__ void async16(unsigned short* lds, const unsigned short* g) {
  __builtin_amdgcn_global_load_lds(
      (const __attribute__((address_space(1))) unsigned int*)g,
      (__attribute__((address_space(3))) unsigned int*)lds, 16, 0, 0);
}
__device__ __forceinline__ float c1raw(int i, int j) {
  float ys = ((float)(i / SW_) + 0.5f) / (float)SH_ * 2.0f - 1.0f;
  float xs = ((float)(i % SW_) + 0.5f) / (float)SW_ * 2.0f - 1.0f;
  float yt = ((float)(j / TW_) + 0.5f) / (float)TH_ * 2.0f - 1.0f;
  float xt = ((float)(j % TW_) + 0.5f) / (float)TW_ * 2.0f - 1.0f;
  return fabsf(ys - yt) + fabsf(xs - xt);
}
__device__ __forceinline__ float blockRedSum(float v) {
  #pragma unroll
  for (int o = 32; o; o >>= 1) v += __shfl_xor(v, o);
  __shared__ float red[4];
  int w = threadIdx.x >> 6;
  if ((threadIdx.x & 63) == 0) red[w] = v;
  __syncthreads();
  float tot = 0.f;
  if (threadIdx.x == 0) {
    int nw = blockDim.x >> 6;
    for (int i = 0; i < nw; i++) tot += red[i];
  }
  return tot;
}

// ---------- small kernels ----------
__global__ __launch_bounds__(256) void initK(unsigned long long* argw, float* normP,
                                             int* c2mn, int* c2mx, int* c1mm, float* accf) {
  int i = blockIdx.x * 256 + threadIdx.x;
  if (i < NIMG * NS) argw[i] = ~0ull;
  if (i < NIMG * NT) normP[i] = 0.f;
  if (i < NIMG) { c2mn[i] = 0x7F800000; c2mx[i] = 0; }
  if (i == 0) { c1mm[0] = 0x7F800000; c1mm[1] = 0; accf[0] = 0.f; accf[1] = 0.f; }
}

__global__ __launch_bounds__(256) void cvtK(const float* __restrict__ in,
                                            unsigned short* __restrict__ out, int n8) {
  int i = blockIdx.x * 256 + threadIdx.x;
  if (i >= n8) return;
  const float4* p = (const float4*)in + (size_t)i * 2;
  bf16x8 v = cvt8(p[0], p[1]);
  *(bf16x8*)(out + (size_t)i * 8) = v;
}

// coalesced transpose W [DT][DSZ] f32 -> Wt [DSZ][DT] bf16
__global__ __launch_bounds__(256) void wtK(const float* __restrict__ W,
                                           unsigned short* __restrict__ Wt) {
  __shared__ float tile[32][33];
  int n0 = blockIdx.x * 32, k0 = blockIdx.y * 32;
  int tx = threadIdx.x & 31, ty = threadIdx.x >> 5;  // ty 0..7
  #pragma unroll
  for (int i = 0; i < 4; i++)
    tile[ty + i * 8][tx] = W[(size_t)(k0 + ty + i * 8) * DSZ + n0 + tx];
  __syncthreads();
  #pragma unroll
  for (int i = 0; i < 4; i++)
    Wt[(size_t)(n0 + ty + i * 8) * DT + k0 + tx] = f2bf(tile[tx][ty + i * 8]);
}

__global__ __launch_bounds__(256) void c1K(int* c1mm) {
  int tid = blockIdx.x * 256 + threadIdx.x;
  float lmin = __builtin_inff(), lmax = 0.f;
  for (int p = tid; p < NS * NT; p += gridDim.x * 256) {
    float v = c1raw(p / NT, p % NT);
    lmin = fminf(lmin, v);
    lmax = fmaxf(lmax, v);
  }
  #pragma unroll
  for (int o = 32; o; o >>= 1) {
    lmin = fminf(lmin, __shfl_xor(lmin, o));
    lmax = fmaxf(lmax, __shfl_xor(lmax, o));
  }
  if ((threadIdx.x & 63) == 0) {
    atomicMin(c1mm, __float_as_int(lmin));
    atomicMax(c1mm + 1, __float_as_int(lmax));
  }
}

__global__ __launch_bounds__(64) void contrK(const float* __restrict__ q,
                                             const float* __restrict__ p, float* accf) {
  int i = blockIdx.x, l = threadIdx.x;
  const float4* qi = (const float4*)(q + (size_t)i * DSZ);
  const float4* pj = (const float4*)(p + (size_t)l * DSZ);
  float dot = 0.f;
  for (int k = 0; k < DSZ / 4; k++) {
    float4 a = qi[k], b = pj[k];
    dot += a.x * b.x + a.y * b.y + a.z * b.z + a.w * b.w;
  }
  float s = dot / TEMPR;
  float m = s;
  #pragma unroll
  for (int o = 32; o; o >>= 1) m = fmaxf(m, __shfl_xor(m, o));
  float e = expf(s - m);
  #pragma unroll
  for (int o = 32; o; o >>= 1) e += __shfl_xor(e, o);
  float lse = m + logf(e);
  float sii = __shfl(s, i);
  if (l == 0) atomicAdd(accf, sii - lse);
}

__global__ __launch_bounds__(256) void normsK(const float* __restrict__ sq,
                                              const float* __restrict__ sp,
                                              float* __restrict__ normS) {
  int r = blockIdx.x;
  int b = r / NS, i = r % NS;
  const float* row = (b < B_IMG) ? sq + ((size_t)b * NS + i) * DSZ
                                 : sp + ((size_t)(b - B_IMG) * NS + i) * DSZ;
  float4 v = ((const float4*)row)[threadIdx.x];
  float s = v.x * v.x + v.y * v.y + v.z * v.z + v.w * v.w;
  float tot = blockRedSum(s);
  if (threadIdx.x == 0) normS[r] = tot;
}

// ---------- GEMM ----------
// MODE 0: proj = teaBf @ Wt^T + b  (M=NT, K=DT, N=DSZ); fused normP accumulation
// MODE 1: G = stu @ proj^T; per-image c2 min/max
// MODE 2: same G; per-row argmin of c1n + 1e-3*c2n
// PRE: A operand available as bf16 (teaBf/stuBf) -> global_load_lds staging
template <int MODE, bool PRE>
__global__ __launch_bounds__(256) void gemmK(
    const float* __restrict__ teaQ, const float* __restrict__ teaP,
    const unsigned short* __restrict__ teaBf, const unsigned short* __restrict__ stuBf,
    const unsigned short* __restrict__ Wt, const float* __restrict__ bias,
    unsigned short* __restrict__ proj, const float* __restrict__ stuQ,
    const float* __restrict__ stuP, const float* __restrict__ normS,
    float* __restrict__ normP, int* __restrict__ c2mn, int* __restrict__ c2mx,
    const int* __restrict__ c1mm, unsigned long long* __restrict__ argw) {
  constexpr int K = (MODE == 0) ? DT : DSZ;
  const int b = blockIdx.y;
  // XCD-friendly: blocks sharing a reuse panel land 8-apart in dispatch order
  const int mt = (MODE == 0) ? (blockIdx.x & 7) : (blockIdx.x >> 3);
  const int nt = (MODE == 0) ? (blockIdx.x >> 3) : (blockIdx.x & 7);
  const int M0 = mt * 128, N0 = nt * 128;

  const unsigned short* Bbf = (MODE == 0) ? Wt : proj + (size_t)b * NT * DSZ;

  __shared__ __align__(16) unsigned short As[128 * 32];
  __shared__ __align__(16) unsigned short Bs[128 * 32];

  const int t = threadIdx.x;
  const int l = t & 63;
  const int w = t >> 6;
  const int wr = w >> 1, wc = w & 1;

  f32x4 acc[4][4];
  #pragma unroll
  for (int i = 0; i < 4; i++)
    #pragma unroll
    for (int j = 0; j < 4; j++) acc[i][j] = (f32x4){0.f, 0.f, 0.f, 0.f};

  // --- staging setup ---
  const unsigned short* gA0; const unsigned short* gA1;
  const unsigned short* gB0; const unsigned short* gB1;
  unsigned short *ldsA0, *ldsA1, *ldsB0, *ldsB1;
  const float* aptrF = nullptr;  // !PRE path
  int arowF = 0, chunkF = 0, swF = 0;
  {
    const unsigned short* Abf;
    if (MODE == 0)
      Abf = teaBf + (size_t)b * NT * DT;
    else
      Abf = stuBf + (size_t)b * NS * DSZ;
    #pragma unroll
    for (int r = 0; r < 2; r++) {
      int p = (w * 2 + r) * 1024 + l * 16;            // byte offset in 8 KB tile
      int row = p >> 6;                               // 64 B per row
      int sl = ((p >> 4) & 3) ^ ((row >> 1) & 3);     // swizzled k-slot
      const unsigned short* ga = Abf + (size_t)(M0 + row) * K + sl * 8;
      const unsigned short* gb = Bbf + (size_t)(N0 + row) * K + sl * 8;
      unsigned short* la = As + (w * 2 + r) * 512;
      unsigned short* lb = Bs + (w * 2 + r) * 512;
      if (r == 0) { gA0 = ga; gB0 = gb; ldsA0 = la; ldsB0 = lb; }
      else        { gA1 = ga; gB1 = gb; ldsA1 = la; ldsB1 = lb; }
    }
    if (!PRE) {
      const float* Af32;
      if (MODE == 0)
        Af32 = (b < B_IMG) ? teaQ + (size_t)b * NT * DT
                           : teaP + (size_t)(b - B_IMG) * NT * DT;
      else
        Af32 = (b < B_IMG) ? stuQ + (size_t)b * NS * DSZ
                           : stuP + (size_t)(b - B_IMG) * NS * DSZ;
      arowF = t >> 1;
      chunkF = t & 1;
      swF = (arowF >> 1) & 3;
      int garow = M0 + arowF;
      if (MODE != 0) garow = min(garow, NS - 1);
      aptrF = Af32 + (size_t)garow * K + chunkF * 16;
    }
  }

  for (int kt = 0; kt < K; kt += 32) {
    if (PRE) {
      async16(ldsA0, gA0); async16(ldsA1, gA1);
      gA0 += 32; gA1 += 32;
    } else {
      const float4* a4 = (const float4*)(aptrF + kt);
      bf16x8 v0 = cvt8(a4[0], a4[1]);
      bf16x8 v1 = cvt8(a4[2], a4[3]);
      *(bf16x8*)&As[arowF * 32 + ((2 * chunkF + 0) ^ swF) * 8] = v0;
      *(bf16x8*)&As[arowF * 32 + ((2 * chunkF + 1) ^ swF) * 8] = v1;
    }
    async16(ldsB0, gB0); async16(ldsB1, gB1);
    gB0 += 32; gB1 += 32;
    __syncthreads();

    bf16x8 af[4], bfv[4];
    #pragma unroll
    for (int mi = 0; mi < 4; mi++) {
      int m = wr * 64 + mi * 16 + (l & 15);
      af[mi] = *(const bf16x8*)&As[m * 32 + (((l >> 4) ^ ((m >> 1) & 3)) * 8)];
    }
    #pragma unroll
    for (int ni = 0; ni < 4; ni++) {
      int n = wc * 64 + ni * 16 + (l & 15);
      bfv[ni] = *(const bf16x8*)&Bs[n * 32 + (((l >> 4) ^ ((n >> 1) & 3)) * 8)];
    }
    #pragma unroll
    for (int mi = 0; mi < 4; mi++)
      #pragma unroll
      for (int ni = 0; ni < 4; ni++)
        acc[mi][ni] =
            __builtin_amdgcn_mfma_f32_16x16x32_bf16(af[mi], bfv[ni], acc[mi][ni], 0, 0, 0);
    __syncthreads();
  }

  const int rbase = (l >> 4) * 4;
  const int cl = l & 15;

  if (MODE == 0) {
    #pragma unroll
    for (int mi = 0; mi < 4; mi++) {
      #pragma unroll
      for (int r = 0; r < 4; r++) {
        int row = M0 + wr * 64 + mi * 16 + rbase + r;
        float vsq = 0.f;
        #pragma unroll
        for (int ni = 0; ni < 4; ni++) {
          int col = N0 + wc * 64 + ni * 16 + cl;
          float v = acc[mi][ni][r] + bias[col];
          proj[((size_t)b * NT + row) * DSZ + col] = f2bf(v);
          vsq += v * v;
        }
        #pragma unroll
        for (int o = 1; o < 16; o <<= 1) vsq += __shfl_xor(vsq, o);
        if (cl == 0) atomicAdd(&normP[b * NT + row], vsq);
      }
    }
  } else if (MODE == 1) {
    float lmin = __builtin_inff(), lmax = -1.f;
    #pragma unroll
    for (int mi = 0; mi < 4; mi++) {
      #pragma unroll
      for (int r = 0; r < 4; r++) {
        int row = M0 + wr * 64 + mi * 16 + rbase + r;
        if (row < NS) {
          float ns = normS[b * NS + row];
          #pragma unroll
          for (int ni = 0; ni < 4; ni++) {
            int col = N0 + wc * 64 + ni * 16 + cl;
            float sq = ns + normP[b * NT + col] - 2.f * acc[mi][ni][r];
            float c2 = sqrtf(fmaxf(sq, 0.f));
            lmin = fminf(lmin, c2);
            lmax = fmaxf(lmax, c2);
          }
        }
      }
    }
    #pragma unroll
    for (int o = 32; o; o >>= 1) {
      lmin = fminf(lmin, __shfl_xor(lmin, o));
      lmax = fmaxf(lmax, __shfl_xor(lmax, o));
    }
    if (l == 0) {
      atomicMin(&c2mn[b], __float_as_int(lmin));
      atomicMax(&c2mx[b], __float_as_int(lmax));
    }
  } else {
    float c1mn = __int_as_float(c1mm[0]);
    float c1mx = __int_as_float(c1mm[1]);
    float c1s = 1.f / (c1mx - c1mn + EPS_);
    float c2mnv = __int_as_float(c2mn[b]);
    float c2mxv = __int_as_float(c2mx[b]);
    float c2s = 1e-3f / (c2mxv - c2mnv + EPS_);
    #pragma unroll
    for (int mi = 0; mi < 4; mi++) {
      #pragma unroll
      for (int r = 0; r < 4; r++) {
        int row = M0 + wr * 64 + mi * 16 + rbase + r;
        unsigned long long key = ~0ull;
        if (row < NS) {
          float ns = normS[b * NS + row];
          #pragma unroll
          for (int ni = 0; ni < 4; ni++) {
            int col = N0 + wc * 64 + ni * 16 + cl;
            float sq = ns + normP[b * NT + col] - 2.f * acc[mi][ni][r];
            float c2 = sqrtf(fmaxf(sq, 0.f));
            float val = (c1raw(row, col) - c1mn) * c1s + (c2 - c2mnv) * c2s;
            unsigned long long k2 =
                ((unsigned long long)(uint32_t)__float_as_int(val) << 32) | (uint32_t)col;
            key = (k2 < key) ? k2 : key;
          }
        }
        #pragma unroll
        for (int o = 1; o < 16; o <<= 1) {
          unsigned long long other = __shfl_xor(key, o);
          key = (other < key) ? other : key;
        }
        if (cl == 0 && row < NS) atomicMin(&argw[(size_t)b * NS + row], key);
      }
    }
  }
}

__global__ __launch_bounds__(256) void mseK(const float* __restrict__ stuQ,
                                            const float* __restrict__ stuP,
                                            const unsigned short* __restrict__ proj,
                                            const unsigned long long* __restrict__ argw,
                                            float* accf) {
  int rr = blockIdx.x;
  int b = rr / NS, i = rr % NS;
  const float* srow = (b < B_IMG) ? stuQ + ((size_t)b * NS + i) * DSZ
                                  : stuP + ((size_t)(b - B_IMG) * NS + i) * DSZ;
  int idx = (int)(argw[rr] & 0xFFFFFFFFull);
  const unsigned short* prow = proj + ((size_t)b * NT + idx) * DSZ;
  float4 s = ((const float4*)srow)[threadIdx.x];
  ushort4 p = ((const ushort4*)prow)[threadIdx.x];
  float d0 = s.x - bf2f(p.x);
  float d1 = s.y - bf2f(p.y);
  float d2 = s.z - bf2f(p.z);
  float d3 = s.w - bf2f(p.w);
  float tot = blockRedSum(d0 * d0 + d1 * d1 + d2 * d2 + d3 * d3);
  if (threadIdx.x == 0) atomicAdd(accf + 1, tot);
}

__global__ void finalK(const float* accf, float* out) {
  float contr = -accf[0] / (float)B_IMG;
  float kd = (accf[1] / (float)(NS * DSZ)) / (2.f * B_IMG + 1e-8f);
  out[0] = contr + kd;
}

extern "C" void kernel_launch(void* const* d_in, const int* in_sizes, int n_in,
                              void* d_out, int out_size, void* d_ws, size_t ws_size,
                              hipStream_t stream) {
  const float* stuQ = (const float*)d_in[0];
  const float* teaQ = (const float*)d_in[1];
  const float* stuP = (const float*)d_in[2];
  const float* teaP = (const float*)d_in[3];
  const float* qreps = (const float*)d_in[4];
  const float* preps = (const float*)d_in[5];
  const float* W = (const float*)d_in[6];
  const float* bias = (const float*)d_in[7];

  if (ws_size < WS_BASIC) return;  // cannot compute
  const bool full = ws_size >= WS_FULL;

  char* ws = (char*)d_ws;
  unsigned short* proj = (unsigned short*)(ws + OFF_PROJ);
  unsigned short* Wt = (unsigned short*)(ws + OFF_WT);
  float* normP = (float*)(ws + OFF_NORMP);
  float* normS = (float*)(ws + OFF_NORMS);
  int* c2mn = (int*)(ws + OFF_C2MIN);
  int* c2mx = (int*)(ws + OFF_C2MAX);
  int* c1mm = (int*)(ws + OFF_C1MM);
  float* accf = (float*)(ws + OFF_ACC);
  unsigned long long* argw = (unsigned long long*)(ws + OFF_ARG);
  unsigned short* teaBf = (unsigned short*)(ws + OFF_TEA);
  unsigned short* stuBf = (unsigned short*)(ws + OFF_STU);
  float* out = (float*)d_out;

  initK<<<dim3(512), dim3(256), 0, stream>>>(argw, normP, c2mn, c2mx, c1mm, accf);
  wtK<<<dim3(DSZ / 32, DT / 32), dim3(256), 0, stream>>>(W, Wt);
  if (full) {
    const int nTea8 = B_IMG * NT * DT / 8;
    const int nStu8 = B_IMG * NS * DSZ / 8;
    cvtK<<<dim3((nTea8 + 255) / 256), dim3(256), 0, stream>>>(teaQ, teaBf, nTea8);
    cvtK<<<dim3((nTea8 + 255) / 256), dim3(256), 0, stream>>>(
        teaP, teaBf + (size_t)B_IMG * NT * DT, nTea8);
    cvtK<<<dim3((nStu8 + 255) / 256), dim3(256), 0, stream>>>(stuQ, stuBf, nStu8);
    cvtK<<<dim3((nStu8 + 255) / 256), dim3(256), 0, stream>>>(
        stuP, stuBf + (size_t)B_IMG * NS * DSZ, nStu8);
  }
  c1K<<<dim3(64), dim3(256), 0, stream>>>(c1mm);
  contrK<<<dim3(B_IMG), dim3(64), 0, stream>>>(qreps, preps, accf);
  normsK<<<dim3(NIMG * NS), dim3(256), 0, stream>>>(stuQ, stuP, normS);

  #define GEMM_ARGS teaQ, teaP, teaBf, stuBf, Wt, bias, proj, stuQ, stuP, \
                    normS, normP, c2mn, c2mx, c1mm, argw
  if (full) {
    gemmK<0, true><<<dim3(64, NIMG), dim3(256), 0, stream>>>(GEMM_ARGS);
    gemmK<1, true><<<dim3(40, NIMG), dim3(256), 0, stream>>>(GEMM_ARGS);
    gemmK<2, true><<<dim3(40, NIMG), dim3(256), 0, stream>>>(GEMM_ARGS);
  } else {
    gemmK<0, false><<<dim3(64, NIMG), dim3(256), 0, stream>>>(GEMM_ARGS);
    gemmK<1, false><<<dim3(40, NIMG), dim3(256), 0, stream>>>(GEMM_ARGS);
    gemmK<2, false><<<dim3(40, NIMG), dim3(256), 0, stream>>>(GEMM_ARGS);
  }
  #undef GEMM_ARGS

  mseK<<<dim3(NIMG * NS), dim3(256), 0, stream>>>(stuQ, stuP, proj, argw, accf);
  finalK<<<dim3(1), dim3(1), 0, stream>>>(accf, out);
}

// Round 3
// 1047.532 us; speedup vs baseline: 2.8510x; 2.2678x over previous
//
#include <hip/hip_runtime.h>
#include <stdint.h>

#define B_IMG 64
#define NIMG 128
#define NS 576
#define NT 1024
#define DSZ 1024
#define DT 1152
#define TEMPR 0.02f

typedef float f32x4 __attribute__((ext_vector_type(4)));
typedef __bf16 bf16x8 __attribute__((ext_vector_type(8)));

// ---------- ws layout ----------
constexpr size_t OFF_PROJ = 0;                                   // bf16 proj [NIMG][NT][DSZ]
constexpr size_t SZ_PROJ = (size_t)NIMG * NT * DSZ * 2;
constexpr size_t OFF_WT = OFF_PROJ + SZ_PROJ;                    // bf16 W^T [DSZ][DT]
constexpr size_t SZ_WT = (size_t)DSZ * DT * 2;
constexpr size_t OFF_NORMP = OFF_WT + SZ_WT;                     // f32 [NIMG*NT]
constexpr size_t OFF_NORMS = OFF_NORMP + (size_t)NIMG * NT * 4;  // f32 [NIMG*NS]
constexpr size_t OFF_ACC = OFF_NORMS + (size_t)NIMG * NS * 4;    // 2 x f32
constexpr size_t OFF_ARG = OFF_ACC + 16;                         // u64 [NIMG*NS]
constexpr size_t SZ_ARG = (size_t)NIMG * NS * 8;
constexpr size_t WS_BASIC = OFF_ARG + SZ_ARG;
constexpr size_t OFF_TEA = (WS_BASIC + 255) & ~(size_t)255;      // bf16 [NIMG][NT][DT]
constexpr size_t SZ_TEA = (size_t)NIMG * NT * DT * 2;
constexpr size_t OFF_STU = OFF_TEA + SZ_TEA;                     // bf16 [NIMG][NS][DSZ] + 64-row pad
constexpr size_t SZ_STU = (size_t)NIMG * NS * DSZ * 2 + 64 * DSZ * 2;
constexpr size_t WS_FULL = OFF_STU + SZ_STU;

// ---------- helpers ----------
__device__ __forceinline__ unsigned short f2bf(float f) {
  union { float f; uint32_t u; } c; c.f = f;
  uint32_t u = c.u;
  uint32_t r = u + 0x7FFFu + ((u >> 16) & 1u);
  return (unsigned short)(r >> 16);
}
__device__ __forceinline__ float bf2f(unsigned short b) {
  union { float f; uint32_t u; } c; c.u = ((uint32_t)b) << 16;
  return c.f;
}
__device__ __forceinline__ bf16x8 cvt8(float4 a, float4 b) {
  bf16x8 r;
  r[0] = (__bf16)a.x; r[1] = (__bf16)a.y; r[2] = (__bf16)a.z; r[3] = (__bf16)a.w;
  r[4] = (__bf16)b.x; r[5] = (__bf16)b.y; r[6] = (__bf16)b.z; r[7] = (__bf16)b.w;
  return r;
}
__device__ __forceinline__ void async16(unsigned short* lds, const unsigned short* g) {
  __builtin_amdgcn_global_load_lds(
      (const __attribute__((address_space(1))) unsigned int*)g,
      (__attribute__((address_space(3))) unsigned int*)lds, 16, 0, 0);
}
// integer c1 rank: c1 * 96 = |2*(4*iy-3*jy)+1| + |2*(4*ix-3*jx)+1|
__device__ __forceinline__ uint32_t c1rank(int row, int col) {
  int iy = row / 24, ix = row - iy * 24;
  int jy = col >> 5, jx = col & 31;
  int a = 2 * (4 * iy - 3 * jy) + 1;
  int bb = 2 * (4 * ix - 3 * jx) + 1;
  return (uint32_t)(abs(a) + abs(bb));
}

// ---------- small kernels ----------
__global__ __launch_bounds__(256) void initK(unsigned long long* argw, float* normP,
                                             float* accf) {
  int i = blockIdx.x * 256 + threadIdx.x;
  if (i < NIMG * NS) argw[i] = ~0ull;
  if (i < NIMG * NT) normP[i] = 0.f;
  if (i == 0) { accf[0] = 0.f; accf[1] = 0.f; }
}

__global__ __launch_bounds__(256) void cvtK(const float* __restrict__ in,
                                            unsigned short* __restrict__ out, int n8) {
  int i = blockIdx.x * 256 + threadIdx.x;
  if (i >= n8) return;
  const float4* p = (const float4*)in + (size_t)i * 2;
  *(bf16x8*)(out + (size_t)i * 8) = cvt8(p[0], p[1]);
}

// convert student rows to bf16 AND compute row norms (2 rows of 1024 per block)
__global__ __launch_bounds__(256) void cvtStuK(const float* __restrict__ in,
                                               unsigned short* __restrict__ out,
                                               float* __restrict__ normS) {
  size_t base = (size_t)blockIdx.x * 2048 + (size_t)threadIdx.x * 8;
  const float4* p = (const float4*)(in + base);
  float4 a = p[0], b = p[1];
  *(bf16x8*)(out + base) = cvt8(a, b);
  float s = a.x * a.x + a.y * a.y + a.z * a.z + a.w * a.w +
            b.x * b.x + b.y * b.y + b.z * b.z + b.w * b.w;
  #pragma unroll
  for (int o = 32; o; o >>= 1) s += __shfl_xor(s, o);
  __shared__ float red[4];
  int t = threadIdx.x;
  if ((t & 63) == 0) red[t >> 6] = s;
  __syncthreads();
  if (t == 0) normS[blockIdx.x * 2] = red[0] + red[1];
  if (t == 128) normS[blockIdx.x * 2 + 1] = red[2] + red[3];
}

// fallback norms (no-bf16-copy path)
__global__ __launch_bounds__(256) void normsK(const float* __restrict__ sq,
                                              const float* __restrict__ sp,
                                              float* __restrict__ normS) {
  int r = blockIdx.x;
  int b = r / NS, i = r % NS;
  const float* row = (b < B_IMG) ? sq + ((size_t)b * NS + i) * DSZ
                                 : sp + ((size_t)(b - B_IMG) * NS + i) * DSZ;
  float4 v = ((const float4*)row)[threadIdx.x];
  float s = v.x * v.x + v.y * v.y + v.z * v.z + v.w * v.w;
  #pragma unroll
  for (int o = 32; o; o >>= 1) s += __shfl_xor(s, o);
  __shared__ float red[4];
  int t = threadIdx.x;
  if ((t & 63) == 0) red[t >> 6] = s;
  __syncthreads();
  if (t == 0) normS[r] = red[0] + red[1] + red[2] + red[3];
}

// coalesced transpose W [DT][DSZ] f32 -> Wt [DSZ][DT] bf16
__global__ __launch_bounds__(256) void wtK(const float* __restrict__ W,
                                           unsigned short* __restrict__ Wt) {
  __shared__ float tile[32][33];
  int n0 = blockIdx.x * 32, k0 = blockIdx.y * 32;
  int tx = threadIdx.x & 31, ty = threadIdx.x >> 5;
  #pragma unroll
  for (int i = 0; i < 4; i++)
    tile[ty + i * 8][tx] = W[(size_t)(k0 + ty + i * 8) * DSZ + n0 + tx];
  __syncthreads();
  #pragma unroll
  for (int i = 0; i < 4; i++)
    Wt[(size_t)(n0 + ty + i * 8) * DT + k0 + tx] = f2bf(tile[tx][ty + i * 8]);
}

__global__ __launch_bounds__(64) void contrK(const float* __restrict__ q,
                                             const float* __restrict__ p, float* accf) {
  int i = blockIdx.x, l = threadIdx.x;
  const float4* qi = (const float4*)(q + (size_t)i * DSZ);
  const float4* pj = (const float4*)(p + (size_t)l * DSZ);
  float dot = 0.f;
  for (int k = 0; k < DSZ / 4; k++) {
    float4 a = qi[k], b = pj[k];
    dot += a.x * b.x + a.y * b.y + a.z * b.z + a.w * b.w;
  }
  float s = dot / TEMPR;
  float m = s;
  #pragma unroll
  for (int o = 32; o; o >>= 1) m = fmaxf(m, __shfl_xor(m, o));
  float e = expf(s - m);
  #pragma unroll
  for (int o = 32; o; o >>= 1) e += __shfl_xor(e, o);
  float lse = m + logf(e);
  float sii = __shfl(s, i);
  if (l == 0) atomicAdd(accf, sii - lse);
}

// ---------- GEMM ----------
// MODE 0: proj = teaBf @ Wt^T + b  (M=NT,K=DT,N=DSZ); fused normP accumulation
// MODE 1: G = stu @ proj^T; per-row lexicographic argmin key (c1i, sq, col)
template <int MODE, bool PRE>
__global__ __launch_bounds__(256) void gemmK(
    const float* __restrict__ teaQ, const float* __restrict__ teaP,
    const unsigned short* __restrict__ teaBf, const unsigned short* __restrict__ stuBf,
    const unsigned short* __restrict__ Wt, const float* __restrict__ bias,
    unsigned short* __restrict__ proj, const float* __restrict__ stuQ,
    const float* __restrict__ stuP, const float* __restrict__ normS,
    float* __restrict__ normP, unsigned long long* __restrict__ argw) {
  constexpr int K = (MODE == 0) ? DT : DSZ;
  const int b = blockIdx.y;
  const int mt = (MODE == 0) ? (blockIdx.x & 7) : (blockIdx.x >> 3);
  const int nt = (MODE == 0) ? (blockIdx.x >> 3) : (blockIdx.x & 7);
  const int M0 = mt * 128, N0 = nt * 128;

  const unsigned short* Bbf = (MODE == 0) ? Wt : proj + (size_t)b * NT * DSZ;

  __shared__ __align__(16) unsigned short As[128 * 32];
  __shared__ __align__(16) unsigned short Bs[128 * 32];

  const int t = threadIdx.x;
  const int l = t & 63;
  const int w = t >> 6;
  const int wr = w >> 1, wc = w & 1;

  f32x4 acc[4][4];
  #pragma unroll
  for (int i = 0; i < 4; i++)
    #pragma unroll
    for (int j = 0; j < 4; j++) acc[i][j] = (f32x4){0.f, 0.f, 0.f, 0.f};

  const unsigned short* gA0; const unsigned short* gA1;
  const unsigned short* gB0; const unsigned short* gB1;
  unsigned short *ldsA0, *ldsA1, *ldsB0, *ldsB1;
  const float* aptrF = nullptr;
  int arowF = 0, chunkF = 0, swF = 0;
  {
    const unsigned short* Abf =
        (MODE == 0) ? teaBf + (size_t)b * NT * DT : stuBf + (size_t)b * NS * DSZ;
    #pragma unroll
    for (int r = 0; r < 2; r++) {
      int p = (w * 2 + r) * 1024 + l * 16;
      int row = p >> 6;
      int sl = ((p >> 4) & 3) ^ ((row >> 1) & 3);
      const unsigned short* ga = Abf + (size_t)(M0 + row) * K + sl * 8;
      const unsigned short* gb = Bbf + (size_t)(N0 + row) * K + sl * 8;
      unsigned short* la = As + (w * 2 + r) * 512;
      unsigned short* lb = Bs + (w * 2 + r) * 512;
      if (r == 0) { gA0 = ga; gB0 = gb; ldsA0 = la; ldsB0 = lb; }
      else        { gA1 = ga; gB1 = gb; ldsA1 = la; ldsB1 = lb; }
    }
    if (!PRE) {
      const float* Af32;
      if (MODE == 0)
        Af32 = (b < B_IMG) ? teaQ + (size_t)b * NT * DT
                           : teaP + (size_t)(b - B_IMG) * NT * DT;
      else
        Af32 = (b < B_IMG) ? stuQ + (size_t)b * NS * DSZ
                           : stuP + (size_t)(b - B_IMG) * NS * DSZ;
      arowF = t >> 1;
      chunkF = t & 1;
      swF = (arowF >> 1) & 3;
      int garow = M0 + arowF;
      if (MODE != 0) garow = min(garow, NS - 1);
      aptrF = Af32 + (size_t)garow * K + chunkF * 16;
    }
  }

  for (int kt = 0; kt < K; kt += 32) {
    if (PRE) {
      async16(ldsA0, gA0); async16(ldsA1, gA1);
      gA0 += 32; gA1 += 32;
    } else {
      const float4* a4 = (const float4*)(aptrF + kt);
      bf16x8 v0 = cvt8(a4[0], a4[1]);
      bf16x8 v1 = cvt8(a4[2], a4[3]);
      *(bf16x8*)&As[arowF * 32 + ((2 * chunkF + 0) ^ swF) * 8] = v0;
      *(bf16x8*)&As[arowF * 32 + ((2 * chunkF + 1) ^ swF) * 8] = v1;
    }
    async16(ldsB0, gB0); async16(ldsB1, gB1);
    gB0 += 32; gB1 += 32;
    __syncthreads();

    bf16x8 af[4], bfv[4];
    #pragma unroll
    for (int mi = 0; mi < 4; mi++) {
      int m = wr * 64 + mi * 16 + (l & 15);
      af[mi] = *(const bf16x8*)&As[m * 32 + (((l >> 4) ^ ((m >> 1) & 3)) * 8)];
    }
    #pragma unroll
    for (int ni = 0; ni < 4; ni++) {
      int n = wc * 64 + ni * 16 + (l & 15);
      bfv[ni] = *(const bf16x8*)&Bs[n * 32 + (((l >> 4) ^ ((n >> 1) & 3)) * 8)];
    }
    #pragma unroll
    for (int mi = 0; mi < 4; mi++)
      #pragma unroll
      for (int ni = 0; ni < 4; ni++)
        acc[mi][ni] =
            __builtin_amdgcn_mfma_f32_16x16x32_bf16(af[mi], bfv[ni], acc[mi][ni], 0, 0, 0);
    __syncthreads();
  }

  const int rbase = (l >> 4) * 4;
  const int cl = l & 15;

  if (MODE == 0) {
    #pragma unroll
    for (int mi = 0; mi < 4; mi++) {
      #pragma unroll
      for (int r = 0; r < 4; r++) {
        int row = M0 + wr * 64 + mi * 16 + rbase + r;
        float vsq = 0.f;
        #pragma unroll
        for (int ni = 0; ni < 4; ni++) {
          int col = N0 + wc * 64 + ni * 16 + cl;
          float v = acc[mi][ni][r] + bias[col];
          proj[((size_t)b * NT + row) * DSZ + col] = f2bf(v);
          vsq += v * v;
        }
        #pragma unroll
        for (int o = 1; o < 16; o <<= 1) vsq += __shfl_xor(vsq, o);
        if (cl == 0) atomicAdd(&normP[b * NT + row], vsq);
      }
    }
  } else {
    #pragma unroll
    for (int mi = 0; mi < 4; mi++) {
      #pragma unroll
      for (int r = 0; r < 4; r++) {
        int row = M0 + wr * 64 + mi * 16 + rbase + r;
        unsigned long long key = ~0ull;
        if (row < NS) {
          float ns = normS[b * NS + row];
          #pragma unroll
          for (int ni = 0; ni < 4; ni++) {
            int col = N0 + wc * 64 + ni * 16 + cl;
            float sq = fmaxf(ns + normP[b * NT + col] - 2.f * acc[mi][ni][r], 0.f);
            unsigned long long k2 =
                ((unsigned long long)c1rank(row, col) << 42) |
                ((unsigned long long)(uint32_t)__float_as_int(sq) << 10) |
                (uint32_t)col;
            key = (k2 < key) ? k2 : key;
          }
        }
        #pragma unroll
        for (int o = 1; o < 16; o <<= 1) {
          unsigned long long other = __shfl_xor(key, o);
          key = (other < key) ? other : key;
        }
        if (cl == 0 && row < NS) atomicMin(&argw[(size_t)b * NS + row], key);
      }
    }
  }
}

// grid-stride MSE gather: per-thread accumulate, ONE atomic per block
__global__ __launch_bounds__(256) void mseK(const float* __restrict__ stuQ,
                                            const float* __restrict__ stuP,
                                            const unsigned short* __restrict__ stuBf,
                                            int useBf,
                                            const unsigned short* __restrict__ proj,
                                            const unsigned long long* __restrict__ argw,
                                            float* accf) {
  const int t = threadIdx.x;
  float acc = 0.f;
  for (int rr = blockIdx.x; rr < NIMG * NS; rr += gridDim.x) {
    int b = rr / NS;
    int idx = (int)(argw[rr] & 1023u);
    const unsigned short* prow = proj + ((size_t)b * NT + idx) * DSZ;
    ushort4 p = ((const ushort4*)prow)[t];
    float d0, d1, d2, d3;
    if (useBf) {
      ushort4 s = ((const ushort4*)(stuBf + (size_t)rr * DSZ))[t];
      d0 = bf2f(s.x) - bf2f(p.x);
      d1 = bf2f(s.y) - bf2f(p.y);
      d2 = bf2f(s.z) - bf2f(p.z);
      d3 = bf2f(s.w) - bf2f(p.w);
    } else {
      int i = rr - b * NS;
      const float* srow = (b < B_IMG) ? stuQ + ((size_t)b * NS + i) * DSZ
                                      : stuP + ((size_t)(b - B_IMG) * NS + i) * DSZ;
      float4 s = ((const float4*)srow)[t];
      d0 = s.x - bf2f(p.x);
      d1 = s.y - bf2f(p.y);
      d2 = s.z - bf2f(p.z);
      d3 = s.w - bf2f(p.w);
    }
    acc += d0 * d0 + d1 * d1 + d2 * d2 + d3 * d3;
  }
  #pragma unroll
  for (int o = 32; o; o >>= 1) acc += __shfl_xor(acc, o);
  __shared__ float red[4];
  if ((t & 63) == 0) red[t >> 6] = acc;
  __syncthreads();
  if (t == 0) atomicAdd(accf + 1, red[0] + red[1] + red[2] + red[3]);
}

__global__ void finalK(const float* accf, float* out) {
  float contr = -accf[0] / (float)B_IMG;
  float kd = (accf[1] / (float)(NS * DSZ)) / (2.f * B_IMG + 1e-8f);
  out[0] = contr + kd;
}

extern "C" void kernel_launch(void* const* d_in, const int* in_sizes, int n_in,
                              void* d_out, int out_size, void* d_ws, size_t ws_size,
                              hipStream_t stream) {
  const float* stuQ = (const float*)d_in[0];
  const float* teaQ = (const float*)d_in[1];
  const float* stuP = (const float*)d_in[2];
  const float* teaP = (const float*)d_in[3];
  const float* qreps = (const float*)d_in[4];
  const float* preps = (const float*)d_in[5];
  const float* W = (const float*)d_in[6];
  const float* bias = (const float*)d_in[7];

  if (ws_size < WS_BASIC) return;
  const bool full = ws_size >= WS_FULL;

  char* ws = (char*)d_ws;
  unsigned short* proj = (unsigned short*)(ws + OFF_PROJ);
  unsigned short* Wt = (unsigned short*)(ws + OFF_WT);
  float* normP = (float*)(ws + OFF_NORMP);
  float* normS = (float*)(ws + OFF_NORMS);
  float* accf = (float*)(ws + OFF_ACC);
  unsigned long long* argw = (unsigned long long*)(ws + OFF_ARG);
  unsigned short* teaBf = (unsigned short*)(ws + OFF_TEA);
  unsigned short* stuBf = (unsigned short*)(ws + OFF_STU);
  float* out = (float*)d_out;

  initK<<<dim3(512), dim3(256), 0, stream>>>(argw, normP, accf);
  wtK<<<dim3(DSZ / 32, DT / 32), dim3(256), 0, stream>>>(W, Wt);
  if (full) {
    const int nTea8 = B_IMG * NT * DT / 8;
    cvtK<<<dim3(nTea8 / 256), dim3(256), 0, stream>>>(teaQ, teaBf, nTea8);
    cvtK<<<dim3(nTea8 / 256), dim3(256), 0, stream>>>(
        teaP, teaBf + (size_t)B_IMG * NT * DT, nTea8);
    const int nStuBlk = B_IMG * NS / 2;  // 2 rows per block
    cvtStuK<<<dim3(nStuBlk), dim3(256), 0, stream>>>(stuQ, stuBf, normS);
    cvtStuK<<<dim3(nStuBlk), dim3(256), 0, stream>>>(
        stuP, stuBf + (size_t)B_IMG * NS * DSZ, normS + B_IMG * NS);
  } else {
    normsK<<<dim3(NIMG * NS), dim3(256), 0, stream>>>(stuQ, stuP, normS);
  }
  contrK<<<dim3(B_IMG), dim3(64), 0, stream>>>(qreps, preps, accf);

  #define GEMM_ARGS teaQ, teaP, teaBf, stuBf, Wt, bias, proj, stuQ, stuP, \
                    normS, normP, argw
  if (full) {
    gemmK<0, true><<<dim3(64, NIMG), dim3(256), 0, stream>>>(GEMM_ARGS);
    gemmK<1, true><<<dim3(40, NIMG), dim3(256), 0, stream>>>(GEMM_ARGS);
  } else {
    gemmK<0, false><<<dim3(64, NIMG), dim3(256), 0, stream>>>(GEMM_ARGS);
    gemmK<1, false><<<dim3(40, NIMG), dim3(256), 0, stream>>>(GEMM_ARGS);
  }
  #undef GEMM_ARGS

  mseK<<<dim3(2048), dim3(256), 0, stream>>>(stuQ, stuP, stuBf, full ? 1 : 0,
                                             proj, argw, accf);
  finalK<<<dim3(1), dim3(1), 0, stream>>>(accf, out);
}

// Round 4
// 782.786 us; speedup vs baseline: 3.8153x; 1.3382x over previous
//
#include <hip/hip_runtime.h>
#include <stdint.h>

#define B_IMG 64
#define NIMG 128
#define NS 576
#define NT 1024
#define DSZ 1024
#define DT 1152
#define TEMPR 0.02f

typedef float f32x4 __attribute__((ext_vector_type(4)));
typedef __bf16 bf16x8 __attribute__((ext_vector_type(8)));

// ---------- ws layout ----------
constexpr size_t OFF_PROJ = 0;                                 // bf16 proj [NIMG][NT][DSZ]
constexpr size_t SZ_PROJ = (size_t)NIMG * NT * DSZ * 2;
constexpr size_t OFF_WT = OFF_PROJ + SZ_PROJ;                  // bf16 W^T [DSZ][DT]
constexpr size_t SZ_WT = (size_t)DSZ * DT * 2;
constexpr size_t OFF_ACC = OFF_WT + SZ_WT;                     // 2 x f32 (contr, kd)
constexpr size_t WS_BASIC = OFF_ACC + 16;
constexpr size_t OFF_TEA = (WS_BASIC + 255) & ~(size_t)255;    // bf16 [NIMG][NT][DT]
constexpr size_t SZ_TEA = (size_t)NIMG * NT * DT * 2;
constexpr size_t WS_FULL = OFF_TEA + SZ_TEA;

// ---------- helpers ----------
__device__ __forceinline__ unsigned short f2bf(float f) {
  union { float f; uint32_t u; } c; c.f = f;
  uint32_t u = c.u;
  uint32_t r = u + 0x7FFFu + ((u >> 16) & 1u);
  return (unsigned short)(r >> 16);
}
__device__ __forceinline__ float bf2f(unsigned short b) {
  union { float f; uint32_t u; } c; c.u = ((uint32_t)b) << 16;
  return c.f;
}
__device__ __forceinline__ bf16x8 cvt8(float4 a, float4 b) {
  bf16x8 r;
  r[0] = (__bf16)a.x; r[1] = (__bf16)a.y; r[2] = (__bf16)a.z; r[3] = (__bf16)a.w;
  r[4] = (__bf16)b.x; r[5] = (__bf16)b.y; r[6] = (__bf16)b.z; r[7] = (__bf16)b.w;
  return r;
}
__device__ __forceinline__ void async16(unsigned short* lds, const unsigned short* g) {
  __builtin_amdgcn_global_load_lds(
      (const __attribute__((address_space(1))) unsigned int*)g,
      (__attribute__((address_space(3))) unsigned int*)lds, 16, 0, 0);
}

// ---------- small kernels ----------
__global__ void initAccK(float* accf) {
  if (threadIdx.x == 0) { accf[0] = 0.f; accf[1] = 0.f; }
}

__global__ __launch_bounds__(256) void cvtK(const float* __restrict__ in,
                                            unsigned short* __restrict__ out, int n8) {
  int i = blockIdx.x * 256 + threadIdx.x;
  if (i >= n8) return;
  const float4* p = (const float4*)in + (size_t)i * 2;
  *(bf16x8*)(out + (size_t)i * 8) = cvt8(p[0], p[1]);
}

// coalesced transpose W [DT][DSZ] f32 -> Wt [DSZ][DT] bf16
__global__ __launch_bounds__(256) void wtK(const float* __restrict__ W,
                                           unsigned short* __restrict__ Wt) {
  __shared__ float tile[32][33];
  int n0 = blockIdx.x * 32, k0 = blockIdx.y * 32;
  int tx = threadIdx.x & 31, ty = threadIdx.x >> 5;
  #pragma unroll
  for (int i = 0; i < 4; i++)
    tile[ty + i * 8][tx] = W[(size_t)(k0 + ty + i * 8) * DSZ + n0 + tx];
  __syncthreads();
  #pragma unroll
  for (int i = 0; i < 4; i++)
    Wt[(size_t)(n0 + ty + i * 8) * DT + k0 + tx] = f2bf(tile[tx][ty + i * 8]);
}

__global__ __launch_bounds__(64) void contrK(const float* __restrict__ q,
                                             const float* __restrict__ p, float* accf) {
  int i = blockIdx.x, l = threadIdx.x;
  const float4* qi = (const float4*)(q + (size_t)i * DSZ);
  const float4* pj = (const float4*)(p + (size_t)l * DSZ);
  float dot = 0.f;
  for (int k = 0; k < DSZ / 4; k++) {
    float4 a = qi[k], b = pj[k];
    dot += a.x * b.x + a.y * b.y + a.z * b.z + a.w * b.w;
  }
  float s = dot / TEMPR;
  float m = s;
  #pragma unroll
  for (int o = 32; o; o >>= 1) m = fmaxf(m, __shfl_xor(m, o));
  float e = expf(s - m);
  #pragma unroll
  for (int o = 32; o; o >>= 1) e += __shfl_xor(e, o);
  float lse = m + logf(e);
  float sii = __shfl(s, i);
  if (l == 0) atomicAdd(accf, sii - lse);
}

// ---------- projection GEMM: proj = teaBf @ Wt^T + b  (M=NT,K=DT,N=DSZ) ----------
template <bool PRE>
__global__ __launch_bounds__(256) void gemmK(
    const float* __restrict__ teaQ, const float* __restrict__ teaP,
    const unsigned short* __restrict__ teaBf, const unsigned short* __restrict__ Wt,
    const float* __restrict__ bias, unsigned short* __restrict__ proj) {
  constexpr int K = DT;
  const int b = blockIdx.y;
  const int mt = blockIdx.x & 7;
  const int nt = blockIdx.x >> 3;
  const int M0 = mt * 128, N0 = nt * 128;

  __shared__ __align__(16) unsigned short As[128 * 32];
  __shared__ __align__(16) unsigned short Bs[128 * 32];

  const int t = threadIdx.x;
  const int l = t & 63;
  const int w = t >> 6;
  const int wr = w >> 1, wc = w & 1;

  f32x4 acc[4][4];
  #pragma unroll
  for (int i = 0; i < 4; i++)
    #pragma unroll
    for (int j = 0; j < 4; j++) acc[i][j] = (f32x4){0.f, 0.f, 0.f, 0.f};

  const unsigned short* gA0; const unsigned short* gA1;
  const unsigned short* gB0; const unsigned short* gB1;
  unsigned short *ldsA0, *ldsA1, *ldsB0, *ldsB1;
  const float* aptrF = nullptr;
  int arowF = 0, chunkF = 0, swF = 0;
  {
    const unsigned short* Abf = teaBf + (size_t)b * NT * DT;
    #pragma unroll
    for (int r = 0; r < 2; r++) {
      int p = (w * 2 + r) * 1024 + l * 16;
      int row = p >> 6;
      int sl = ((p >> 4) & 3) ^ ((row >> 1) & 3);
      const unsigned short* ga = Abf + (size_t)(M0 + row) * K + sl * 8;
      const unsigned short* gb = Wt + (size_t)(N0 + row) * K + sl * 8;
      unsigned short* la = As + (w * 2 + r) * 512;
      unsigned short* lb = Bs + (w * 2 + r) * 512;
      if (r == 0) { gA0 = ga; gB0 = gb; ldsA0 = la; ldsB0 = lb; }
      else        { gA1 = ga; gB1 = gb; ldsA1 = la; ldsB1 = lb; }
    }
    if (!PRE) {
      const float* Af32 = (b < B_IMG) ? teaQ + (size_t)b * NT * DT
                                      : teaP + (size_t)(b - B_IMG) * NT * DT;
      arowF = t >> 1;
      chunkF = t & 1;
      swF = (arowF >> 1) & 3;
      aptrF = Af32 + (size_t)(M0 + arowF) * K + chunkF * 16;
    }
  }

  for (int kt = 0; kt < K; kt += 32) {
    if (PRE) {
      async16(ldsA0, gA0); async16(ldsA1, gA1);
      gA0 += 32; gA1 += 32;
    } else {
      const float4* a4 = (const float4*)(aptrF + kt);
      bf16x8 v0 = cvt8(a4[0], a4[1]);
      bf16x8 v1 = cvt8(a4[2], a4[3]);
      *(bf16x8*)&As[arowF * 32 + ((2 * chunkF + 0) ^ swF) * 8] = v0;
      *(bf16x8*)&As[arowF * 32 + ((2 * chunkF + 1) ^ swF) * 8] = v1;
    }
    async16(ldsB0, gB0); async16(ldsB1, gB1);
    gB0 += 32; gB1 += 32;
    __syncthreads();

    bf16x8 af[4], bfv[4];
    #pragma unroll
    for (int mi = 0; mi < 4; mi++) {
      int m = wr * 64 + mi * 16 + (l & 15);
      af[mi] = *(const bf16x8*)&As[m * 32 + (((l >> 4) ^ ((m >> 1) & 3)) * 8)];
    }
    #pragma unroll
    for (int ni = 0; ni < 4; ni++) {
      int n = wc * 64 + ni * 16 + (l & 15);
      bfv[ni] = *(const bf16x8*)&Bs[n * 32 + (((l >> 4) ^ ((n >> 1) & 3)) * 8)];
    }
    #pragma unroll
    for (int mi = 0; mi < 4; mi++)
      #pragma unroll
      for (int ni = 0; ni < 4; ni++)
        acc[mi][ni] =
            __builtin_amdgcn_mfma_f32_16x16x32_bf16(af[mi], bfv[ni], acc[mi][ni], 0, 0, 0);
    __syncthreads();
  }

  const int rbase = (l >> 4) * 4;
  const int cl = l & 15;
  #pragma unroll
  for (int mi = 0; mi < 4; mi++) {
    #pragma unroll
    for (int r = 0; r < 4; r++) {
      int row = M0 + wr * 64 + mi * 16 + rbase + r;
      #pragma unroll
      for (int ni = 0; ni < 4; ni++) {
        int col = N0 + wc * 64 + ni * 16 + cl;
        proj[((size_t)b * NT + row) * DSZ + col] = f2bf(acc[mi][ni][r] + bias[col]);
      }
    }
  }
}

// ---------- candidate-match + MSE in one pass ----------
// For student row (iy,ix), the minimal-c1 teacher cells are the closed-form
// candidates below (<=4); c2 (i.e. squared distance) breaks ties among them,
// then lowest col. The winning squared distance IS the row's MSE numerator.
__global__ __launch_bounds__(256) void candK(const float* __restrict__ stuQ,
                                             const float* __restrict__ stuP,
                                             const unsigned short* __restrict__ proj,
                                             float* accf) {
  const int l = threadIdx.x & 63;
  const int w = threadIdx.x >> 6;
  const int gw = blockIdx.x * 4 + w;  // 8192 waves x 9 rows = 73728 rows
  float acc = 0.f;
  #pragma unroll 1
  for (int k = 0; k < 9; k++) {
    int rr = gw * 9 + k;
    int b = rr / NS, i = rr - b * NS;
    const float* srow = (b < B_IMG) ? stuQ + ((size_t)b * NS + i) * DSZ
                                    : stuP + ((size_t)(b - B_IMG) * NS + i) * DSZ;
    const float4* sp = (const float4*)(srow + l * 16);
    float4 s0 = sp[0], s1 = sp[1], s2 = sp[2], s3 = sp[3];

    int iy = i / 24, ix = i - iy * 24;
    int ry = iy % 3, rx = ix % 3;
    int jy0, jy1, jx0, jx1;
    if (ry == 0)      { jy0 = jy1 = (4 * iy) / 3; }
    else if (ry == 1) { jy0 = (4 * iy - 1) / 3; jy1 = (4 * iy + 2) / 3; }
    else              { jy0 = jy1 = (4 * iy + 1) / 3; }
    if (rx == 0)      { jx0 = jx1 = (4 * ix) / 3; }
    else if (rx == 1) { jx0 = (4 * ix - 1) / 3; jx1 = (4 * ix + 2) / 3; }
    else              { jx0 = jx1 = (4 * ix + 1) / 3; }

    const unsigned short* pbase = proj + (size_t)b * NT * DSZ;
    float best = __builtin_inff();
    #pragma unroll
    for (int cy = 0; cy < 2; cy++) {
      int jy = cy ? jy1 : jy0;
      if (cy && jy1 == jy0) continue;
      #pragma unroll
      for (int cx = 0; cx < 2; cx++) {
        int jx = cx ? jx1 : jx0;
        if (cx && jx1 == jx0) continue;
        int col = jy * 32 + jx;
        const uint4* pr = (const uint4*)(pbase + (size_t)col * DSZ + l * 16);
        uint4 p0 = pr[0], p1 = pr[1];
        float sq = 0.f;
        {
          float d;
          d = s0.x - bf2f((unsigned short)(p0.x & 0xFFFF)); sq += d * d;
          d = s0.y - bf2f((unsigned short)(p0.x >> 16));    sq += d * d;
          d = s0.z - bf2f((unsigned short)(p0.y & 0xFFFF)); sq += d * d;
          d = s0.w - bf2f((unsigned short)(p0.y >> 16));    sq += d * d;
          d = s1.x - bf2f((unsigned short)(p0.z & 0xFFFF)); sq += d * d;
          d = s1.y - bf2f((unsigned short)(p0.z >> 16));    sq += d * d;
          d = s1.z - bf2f((unsigned short)(p0.w & 0xFFFF)); sq += d * d;
          d = s1.w - bf2f((unsigned short)(p0.w >> 16));    sq += d * d;
          d = s2.x - bf2f((unsigned short)(p1.x & 0xFFFF)); sq += d * d;
          d = s2.y - bf2f((unsigned short)(p1.x >> 16));    sq += d * d;
          d = s2.z - bf2f((unsigned short)(p1.y & 0xFFFF)); sq += d * d;
          d = s2.w - bf2f((unsigned short)(p1.y >> 16));    sq += d * d;
          d = s3.x - bf2f((unsigned short)(p1.z & 0xFFFF)); sq += d * d;
          d = s3.y - bf2f((unsigned short)(p1.z >> 16));    sq += d * d;
          d = s3.z - bf2f((unsigned short)(p1.w & 0xFFFF)); sq += d * d;
          d = s3.w - bf2f((unsigned short)(p1.w >> 16));    sq += d * d;
        }
        #pragma unroll
        for (int o = 32; o; o >>= 1) sq += __shfl_xor(sq, o);
        if (sq < best) best = sq;  // candidates visited in increasing col order
      }
    }
    acc += best;
  }
  __shared__ float red[4];
  if (l == 0) red[w] = acc;
  __syncthreads();
  if (threadIdx.x == 0)
    atomicAdd(accf + 1, red[0] + red[1] + red[2] + red[3]);
}

__global__ void finalK(const float* accf, float* out) {
  float contr = -accf[0] / (float)B_IMG;
  float kd = (accf[1] / (float)(NS * DSZ)) / (2.f * B_IMG + 1e-8f);
  out[0] = contr + kd;
}

extern "C" void kernel_launch(void* const* d_in, const int* in_sizes, int n_in,
                              void* d_out, int out_size, void* d_ws, size_t ws_size,
                              hipStream_t stream) {
  const float* stuQ = (const float*)d_in[0];
  const float* teaQ = (const float*)d_in[1];
  const float* stuP = (const float*)d_in[2];
  const float* teaP = (const float*)d_in[3];
  const float* qreps = (const float*)d_in[4];
  const float* preps = (const float*)d_in[5];
  const float* W = (const float*)d_in[6];
  const float* bias = (const float*)d_in[7];

  if (ws_size < WS_BASIC) return;
  const bool full = ws_size >= WS_FULL;

  char* ws = (char*)d_ws;
  unsigned short* proj = (unsigned short*)(ws + OFF_PROJ);
  unsigned short* Wt = (unsigned short*)(ws + OFF_WT);
  float* accf = (float*)(ws + OFF_ACC);
  unsigned short* teaBf = (unsigned short*)(ws + OFF_TEA);
  float* out = (float*)d_out;

  initAccK<<<dim3(1), dim3(64), 0, stream>>>(accf);
  wtK<<<dim3(DSZ / 32, DT / 32), dim3(256), 0, stream>>>(W, Wt);
  if (full) {
    const int nTea8 = B_IMG * NT * DT / 8;
    cvtK<<<dim3(nTea8 / 256), dim3(256), 0, stream>>>(teaQ, teaBf, nTea8);
    cvtK<<<dim3(nTea8 / 256), dim3(256), 0, stream>>>(
        teaP, teaBf + (size_t)B_IMG * NT * DT, nTea8);
  }
  contrK<<<dim3(B_IMG), dim3(64), 0, stream>>>(qreps, preps, accf);

  if (full)
    gemmK<true><<<dim3(64, NIMG), dim3(256), 0, stream>>>(teaQ, teaP, teaBf, Wt, bias, proj);
  else
    gemmK<false><<<dim3(64, NIMG), dim3(256), 0, stream>>>(teaQ, teaP, teaBf, Wt, bias, proj);

  candK<<<dim3(2048), dim3(256), 0, stream>>>(stuQ, stuP, proj, accf);
  finalK<<<dim3(1), dim3(1), 0, stream>>>(accf, out);
}

// Round 5
// 686.617 us; speedup vs baseline: 4.3497x; 1.1401x over previous
//
#include <hip/hip_runtime.h>
#include <stdint.h>

#define B_IMG 64
#define NIMG 128
#define NS 576
#define NT 1024
#define DSZ 1024
#define DT 1152
#define TEMPR 0.02f

typedef float f32x4 __attribute__((ext_vector_type(4)));
typedef __bf16 bf16x8 __attribute__((ext_vector_type(8)));

// ---------- ws layout ----------
constexpr size_t OFF_PROJ = 0;                                 // bf16 proj [NIMG][NT][DSZ]
constexpr size_t SZ_PROJ = (size_t)NIMG * NT * DSZ * 2;
constexpr size_t OFF_WT = OFF_PROJ + SZ_PROJ;                  // bf16 W^T [DSZ][DT]
constexpr size_t SZ_WT = (size_t)DSZ * DT * 2;
constexpr size_t OFF_ACC = OFF_WT + SZ_WT;                     // 2 x f32 (contr, kd)
constexpr size_t WS_BASIC = OFF_ACC + 16;
constexpr size_t OFF_TEA = (WS_BASIC + 255) & ~(size_t)255;    // bf16 [NIMG][NT][DT]
constexpr size_t SZ_TEA = (size_t)NIMG * NT * DT * 2;
constexpr size_t WS_FULL = OFF_TEA + SZ_TEA;

// ---------- helpers ----------
__device__ __forceinline__ unsigned short f2bf(float f) {
  union { float f; uint32_t u; } c; c.f = f;
  uint32_t u = c.u;
  uint32_t r = u + 0x7FFFu + ((u >> 16) & 1u);
  return (unsigned short)(r >> 16);
}
__device__ __forceinline__ float bf2f(unsigned short b) {
  union { float f; uint32_t u; } c; c.u = ((uint32_t)b) << 16;
  return c.f;
}
__device__ __forceinline__ bf16x8 cvt8(float4 a, float4 b) {
  bf16x8 r;
  r[0] = (__bf16)a.x; r[1] = (__bf16)a.y; r[2] = (__bf16)a.z; r[3] = (__bf16)a.w;
  r[4] = (__bf16)b.x; r[5] = (__bf16)b.y; r[6] = (__bf16)b.z; r[7] = (__bf16)b.w;
  return r;
}
__device__ __forceinline__ void async16(unsigned short* lds, const unsigned short* g) {
  __builtin_amdgcn_global_load_lds(
      (const __attribute__((address_space(1))) unsigned int*)g,
      (__attribute__((address_space(3))) unsigned int*)lds, 16, 0, 0);
}

// ---------- small kernels ----------
__global__ void initAccK(float* accf) {
  if (threadIdx.x == 0) { accf[0] = 0.f; accf[1] = 0.f; }
}

__global__ __launch_bounds__(256) void cvtK(const float* __restrict__ in,
                                            unsigned short* __restrict__ out, int n8) {
  int i = blockIdx.x * 256 + threadIdx.x;
  if (i >= n8) return;
  const float4* p = (const float4*)in + (size_t)i * 2;
  *(bf16x8*)(out + (size_t)i * 8) = cvt8(p[0], p[1]);
}

// coalesced transpose W [DT][DSZ] f32 -> Wt [DSZ][DT] bf16
__global__ __launch_bounds__(256) void wtK(const float* __restrict__ W,
                                           unsigned short* __restrict__ Wt) {
  __shared__ float tile[32][33];
  int n0 = blockIdx.x * 32, k0 = blockIdx.y * 32;
  int tx = threadIdx.x & 31, ty = threadIdx.x >> 5;
  #pragma unroll
  for (int i = 0; i < 4; i++)
    tile[ty + i * 8][tx] = W[(size_t)(k0 + ty + i * 8) * DSZ + n0 + tx];
  __syncthreads();
  #pragma unroll
  for (int i = 0; i < 4; i++)
    Wt[(size_t)(n0 + ty + i * 8) * DT + k0 + tx] = f2bf(tile[tx][ty + i * 8]);
}

__global__ __launch_bounds__(64) void contrK(const float* __restrict__ q,
                                             const float* __restrict__ p, float* accf) {
  int i = blockIdx.x, l = threadIdx.x;
  const float4* qi = (const float4*)(q + (size_t)i * DSZ);
  const float4* pj = (const float4*)(p + (size_t)l * DSZ);
  float dot = 0.f;
  for (int k = 0; k < DSZ / 4; k++) {
    float4 a = qi[k], b = pj[k];
    dot += a.x * b.x + a.y * b.y + a.z * b.z + a.w * b.w;
  }
  float s = dot / TEMPR;
  float m = s;
  #pragma unroll
  for (int o = 32; o; o >>= 1) m = fmaxf(m, __shfl_xor(m, o));
  float e = expf(s - m);
  #pragma unroll
  for (int o = 32; o; o >>= 1) e += __shfl_xor(e, o);
  float lse = m + logf(e);
  float sii = __shfl(s, i);
  if (l == 0) atomicAdd(accf, sii - lse);
}

// ---------- 256x256 deep-pipelined projection GEMM ----------
// proj = teaBf @ Wt^T + b  (M=NT=1024, K=DT=1152, N=DSZ=1024)
// 8 waves (2Mx4N), wave tile 128x64; BK=32; 4-deep LDS pipeline, counted vmcnt.
__global__ __launch_bounds__(512, 2) void gemm256K(
    const unsigned short* __restrict__ teaBf, const unsigned short* __restrict__ Wt,
    const float* __restrict__ bias, unsigned short* __restrict__ proj) {
  const int b = blockIdx.y;
  const int mt = blockIdx.x & 3;
  const int nt = blockIdx.x >> 2;
  const int M0 = mt * 256, N0 = nt * 256;

  // [buf][A=0/B=1][256 rows x 32 k], slot-XOR swizzled rows (64B rows)
  __shared__ __align__(16) unsigned short lds[4][2][256 * 32];

  const int t = threadIdx.x;
  const int l = t & 63;
  const int w = t >> 6;
  const int wr = w >> 2;  // 0..1
  const int wc = w & 3;   // 0..3

  f32x4 acc[8][4];
  #pragma unroll
  for (int i = 0; i < 8; i++)
    #pragma unroll
    for (int j = 0; j < 4; j++) acc[i][j] = (f32x4){0.f, 0.f, 0.f, 0.f};

  // staging: round r in {0,1}: tile byte p=(r*512+t)*16; row=p>>6; swizzled k-slot
  const unsigned short* Abase = teaBf + (size_t)(b * NT + M0) * DT;
  const unsigned short* Bbase = Wt + (size_t)N0 * DT;
  const int row0 = t >> 2;
  const int row1 = (512 + t) >> 2;
  const int sl0 = (t & 3) ^ ((row0 >> 1) & 3);
  const int sl1 = (t & 3) ^ ((row1 >> 1) & 3);
  const unsigned short* gA0 = Abase + (size_t)row0 * DT + sl0 * 8;
  const unsigned short* gA1 = Abase + (size_t)row1 * DT + sl1 * 8;
  const unsigned short* gB0 = Bbase + (size_t)row0 * DT + sl0 * 8;
  const unsigned short* gB1 = Bbase + (size_t)row1 * DT + sl1 * 8;
  const int st0 = t * 8;          // ushort offset, linear
  const int st1 = (512 + t) * 8;

#define STAGE(TT) {                                      \
    int bf_ = (TT) & 3; int ko_ = (TT) * 32;             \
    async16(&lds[bf_][0][st0], gA0 + ko_);               \
    async16(&lds[bf_][0][st1], gA1 + ko_);               \
    async16(&lds[bf_][1][st0], gB0 + ko_);               \
    async16(&lds[bf_][1][st1], gB1 + ko_); }

  // fragment LDS offsets (same swizzle as staging)
  int aOff[8], bOff[4];
  #pragma unroll
  for (int mi = 0; mi < 8; mi++) {
    int m = wr * 128 + mi * 16 + (l & 15);
    aOff[mi] = m * 32 + (((l >> 4) ^ ((m >> 1) & 3)) * 8);
  }
  #pragma unroll
  for (int ni = 0; ni < 4; ni++) {
    int n = wc * 64 + ni * 16 + (l & 15);
    bOff[ni] = n * 32 + (((l >> 4) ^ ((n >> 1) & 3)) * 8);
  }

#define K_ITER(KT, VMLIT, DO_STG) {                                        \
    asm volatile("s_waitcnt vmcnt(" VMLIT ")" ::: "memory");               \
    __builtin_amdgcn_s_barrier();                                          \
    asm volatile("" ::: "memory");                                         \
    if (DO_STG) STAGE((KT) + 3);                                           \
    const unsigned short* aS = &lds[(KT) & 3][0][0];                       \
    const unsigned short* bS = &lds[(KT) & 3][1][0];                       \
    bf16x8 af[8], bfv[4];                                                  \
    _Pragma("unroll")                                                      \
    for (int mi = 0; mi < 8; mi++) af[mi] = *(const bf16x8*)&aS[aOff[mi]]; \
    _Pragma("unroll")                                                      \
    for (int ni = 0; ni < 4; ni++) bfv[ni] = *(const bf16x8*)&bS[bOff[ni]];\
    __builtin_amdgcn_s_setprio(1);                                         \
    _Pragma("unroll")                                                      \
    for (int mi = 0; mi < 8; mi++)                                         \
      _Pragma("unroll")                                                    \
      for (int ni = 0; ni < 4; ni++)                                       \
        acc[mi][ni] = __builtin_amdgcn_mfma_f32_16x16x32_bf16(             \
            af[mi], bfv[ni], acc[mi][ni], 0, 0, 0);                        \
    __builtin_amdgcn_s_setprio(0); }

  // prologue: 3 K-tiles in flight
  STAGE(0); STAGE(1); STAGE(2);
  // steady state: vmcnt(8) drains exactly K-tile kt (kt+1,kt+2 stay in flight)
  for (int kt = 0; kt < 33; kt++) { K_ITER(kt, "8", true); }
  K_ITER(33, "8", false);
  K_ITER(34, "4", false);
  K_ITER(35, "0", false);
#undef K_ITER
#undef STAGE

  // epilogue: bias + bf16 store
  const int rbase = (l >> 4) * 4;
  const int cl = l & 15;
  #pragma unroll
  for (int ni = 0; ni < 4; ni++) {
    int col = N0 + wc * 64 + ni * 16 + cl;
    float bv = bias[col];
    #pragma unroll
    for (int mi = 0; mi < 8; mi++) {
      int row = M0 + wr * 128 + mi * 16 + rbase;
      #pragma unroll
      for (int r = 0; r < 4; r++)
        proj[((size_t)b * NT + row + r) * DSZ + col] = f2bf(acc[mi][ni][r] + bv);
    }
  }
}

// ---------- fallback 128x128 GEMM (small-ws path, converts A in-kernel) ----------
__global__ __launch_bounds__(256) void gemmFbK(
    const float* __restrict__ teaQ, const float* __restrict__ teaP,
    const unsigned short* __restrict__ Wt, const float* __restrict__ bias,
    unsigned short* __restrict__ proj) {
  constexpr int K = DT;
  const int b = blockIdx.y;
  const int mt = blockIdx.x & 7;
  const int nt = blockIdx.x >> 3;
  const int M0 = mt * 128, N0 = nt * 128;

  __shared__ __align__(16) unsigned short As[128 * 32];
  __shared__ __align__(16) unsigned short Bs[128 * 32];

  const int t = threadIdx.x;
  const int l = t & 63;
  const int w = t >> 6;
  const int wr = w >> 1, wc = w & 1;

  f32x4 acc[4][4];
  #pragma unroll
  for (int i = 0; i < 4; i++)
    #pragma unroll
    for (int j = 0; j < 4; j++) acc[i][j] = (f32x4){0.f, 0.f, 0.f, 0.f};

  const float* Af32 = (b < B_IMG) ? teaQ + (size_t)b * NT * DT
                                  : teaP + (size_t)(b - B_IMG) * NT * DT;
  const int arowF = t >> 1;
  const int chunkF = t & 1;
  const int swF = (arowF >> 1) & 3;
  const float* aptrF = Af32 + (size_t)(M0 + arowF) * K + chunkF * 16;

  int prow = (t * 16) >> 6;
  int psl = ((t * 16 >> 4) & 3) ^ ((prow >> 1) & 3);
  const unsigned short* gB0 = Wt + (size_t)(N0 + prow) * K + psl * 8;
  int prow1 = ((t + 256) * 16) >> 6;
  int psl1 = (((t + 256) * 16 >> 4) & 3) ^ ((prow1 >> 1) & 3);
  const unsigned short* gB1 = Wt + (size_t)(N0 + prow1) * K + psl1 * 8;
  unsigned short* ldsB0 = Bs + t * 8;
  unsigned short* ldsB1 = Bs + (t + 256) * 8;

  for (int kt = 0; kt < K; kt += 32) {
    const float4* a4 = (const float4*)(aptrF + kt);
    bf16x8 v0 = cvt8(a4[0], a4[1]);
    bf16x8 v1 = cvt8(a4[2], a4[3]);
    *(bf16x8*)&As[arowF * 32 + ((2 * chunkF + 0) ^ swF) * 8] = v0;
    *(bf16x8*)&As[arowF * 32 + ((2 * chunkF + 1) ^ swF) * 8] = v1;
    async16(ldsB0, gB0 + kt);
    async16(ldsB1, gB1 + kt);
    __syncthreads();

    bf16x8 af[4], bfv[4];
    #pragma unroll
    for (int mi = 0; mi < 4; mi++) {
      int m = wr * 64 + mi * 16 + (l & 15);
      af[mi] = *(const bf16x8*)&As[m * 32 + (((l >> 4) ^ ((m >> 1) & 3)) * 8)];
    }
    #pragma unroll
    for (int ni = 0; ni < 4; ni++) {
      int n = wc * 64 + ni * 16 + (l & 15);
      bfv[ni] = *(const bf16x8*)&Bs[n * 32 + (((l >> 4) ^ ((n >> 1) & 3)) * 8)];
    }
    #pragma unroll
    for (int mi = 0; mi < 4; mi++)
      #pragma unroll
      for (int ni = 0; ni < 4; ni++)
        acc[mi][ni] =
            __builtin_amdgcn_mfma_f32_16x16x32_bf16(af[mi], bfv[ni], acc[mi][ni], 0, 0, 0);
    __syncthreads();
  }

  const int rbase = (l >> 4) * 4;
  const int cl = l & 15;
  #pragma unroll
  for (int ni = 0; ni < 4; ni++) {
    int col = N0 + wc * 64 + ni * 16 + cl;
    float bv = bias[col];
    #pragma unroll
    for (int mi = 0; mi < 4; mi++) {
      int row = M0 + wr * 64 + mi * 16 + rbase;
      #pragma unroll
      for (int r = 0; r < 4; r++)
        proj[((size_t)b * NT + row + r) * DSZ + col] = f2bf(acc[mi][ni][r] + bv);
    }
  }
}

// ---------- candidate-match + MSE in one pass ----------
__global__ __launch_bounds__(256) void candK(const float* __restrict__ stuQ,
                                             const float* __restrict__ stuP,
                                             const unsigned short* __restrict__ proj,
                                             float* accf) {
  const int l = threadIdx.x & 63;
  const int w = threadIdx.x >> 6;
  const int gw = blockIdx.x * 4 + w;  // 8192 waves x 9 rows = 73728 rows
  float acc = 0.f;
  #pragma unroll 1
  for (int k = 0; k < 9; k++) {
    int rr = gw * 9 + k;
    int b = rr / NS, i = rr - b * NS;
    const float* srow = (b < B_IMG) ? stuQ + ((size_t)b * NS + i) * DSZ
                                    : stuP + ((size_t)(b - B_IMG) * NS + i) * DSZ;
    const float4* sp = (const float4*)(srow + l * 16);
    float4 s0 = sp[0], s1 = sp[1], s2 = sp[2], s3 = sp[3];

    int iy = i / 24, ix = i - iy * 24;
    int ry = iy % 3, rx = ix % 3;
    int jy0, jy1, jx0, jx1;
    if (ry == 0)      { jy0 = jy1 = (4 * iy) / 3; }
    else if (ry == 1) { jy0 = (4 * iy - 1) / 3; jy1 = (4 * iy + 2) / 3; }
    else              { jy0 = jy1 = (4 * iy + 1) / 3; }
    if (rx == 0)      { jx0 = jx1 = (4 * ix) / 3; }
    else if (rx == 1) { jx0 = (4 * ix - 1) / 3; jx1 = (4 * ix + 2) / 3; }
    else              { jx0 = jx1 = (4 * ix + 1) / 3; }

    const unsigned short* pbase = proj + (size_t)b * NT * DSZ;
    float best = __builtin_inff();
    #pragma unroll
    for (int cy = 0; cy < 2; cy++) {
      int jy = cy ? jy1 : jy0;
      if (cy && jy1 == jy0) continue;
      #pragma unroll
      for (int cx = 0; cx < 2; cx++) {
        int jx = cx ? jx1 : jx0;
        if (cx && jx1 == jx0) continue;
        int col = jy * 32 + jx;
        const uint4* pr = (const uint4*)(pbase + (size_t)col * DSZ + l * 16);
        uint4 p0 = pr[0], p1 = pr[1];
        float sq = 0.f;
        {
          float d;
          d = s0.x - bf2f((unsigned short)(p0.x & 0xFFFF)); sq += d * d;
          d = s0.y - bf2f((unsigned short)(p0.x >> 16));    sq += d * d;
          d = s0.z - bf2f((unsigned short)(p0.y & 0xFFFF)); sq += d * d;
          d = s0.w - bf2f((unsigned short)(p0.y >> 16));    sq += d * d;
          d = s1.x - bf2f((unsigned short)(p0.z & 0xFFFF)); sq += d * d;
          d = s1.y - bf2f((unsigned short)(p0.z >> 16));    sq += d * d;
          d = s1.z - bf2f((unsigned short)(p0.w & 0xFFFF)); sq += d * d;
          d = s1.w - bf2f((unsigned short)(p0.w >> 16));    sq += d * d;
          d = s2.x - bf2f((unsigned short)(p1.x & 0xFFFF)); sq += d * d;
          d = s2.y - bf2f((unsigned short)(p1.x >> 16));    sq += d * d;
          d = s2.z - bf2f((unsigned short)(p1.y & 0xFFFF)); sq += d * d;
          d = s2.w - bf2f((unsigned short)(p1.y >> 16));    sq += d * d;
          d = s3.x - bf2f((unsigned short)(p1.z & 0xFFFF)); sq += d * d;
          d = s3.y - bf2f((unsigned short)(p1.z >> 16));    sq += d * d;
          d = s3.z - bf2f((unsigned short)(p1.w & 0xFFFF)); sq += d * d;
          d = s3.w - bf2f((unsigned short)(p1.w >> 16));    sq += d * d;
        }
        #pragma unroll
        for (int o = 32; o; o >>= 1) sq += __shfl_xor(sq, o);
        if (sq < best) best = sq;  // increasing col order => first-occurrence ties
      }
    }
    acc += best;
  }
  __shared__ float red[4];
  if (l == 0) red[w] = acc;
  __syncthreads();
  if (threadIdx.x == 0)
    atomicAdd(accf + 1, red[0] + red[1] + red[2] + red[3]);
}

__global__ void finalK(const float* accf, float* out) {
  float contr = -accf[0] / (float)B_IMG;
  float kd = (accf[1] / (float)(NS * DSZ)) / (2.f * B_IMG + 1e-8f);
  out[0] = contr + kd;
}

extern "C" void kernel_launch(void* const* d_in, const int* in_sizes, int n_in,
                              void* d_out, int out_size, void* d_ws, size_t ws_size,
                              hipStream_t stream) {
  const float* stuQ = (const float*)d_in[0];
  const float* teaQ = (const float*)d_in[1];
  const float* stuP = (const float*)d_in[2];
  const float* teaP = (const float*)d_in[3];
  const float* qreps = (const float*)d_in[4];
  const float* preps = (const float*)d_in[5];
  const float* W = (const float*)d_in[6];
  const float* bias = (const float*)d_in[7];

  if (ws_size < WS_BASIC) return;
  const bool full = ws_size >= WS_FULL;

  char* ws = (char*)d_ws;
  unsigned short* proj = (unsigned short*)(ws + OFF_PROJ);
  unsigned short* Wt = (unsigned short*)(ws + OFF_WT);
  float* accf = (float*)(ws + OFF_ACC);
  unsigned short* teaBf = (unsigned short*)(ws + OFF_TEA);
  float* out = (float*)d_out;

  initAccK<<<dim3(1), dim3(64), 0, stream>>>(accf);
  wtK<<<dim3(DSZ / 32, DT / 32), dim3(256), 0, stream>>>(W, Wt);
  if (full) {
    const int nTea8 = B_IMG * NT * DT / 8;
    cvtK<<<dim3(nTea8 / 256), dim3(256), 0, stream>>>(teaQ, teaBf, nTea8);
    cvtK<<<dim3(nTea8 / 256), dim3(256), 0, stream>>>(
        teaP, teaBf + (size_t)B_IMG * NT * DT, nTea8);
  }
  contrK<<<dim3(B_IMG), dim3(64), 0, stream>>>(qreps, preps, accf);

  if (full)
    gemm256K<<<dim3(16, NIMG), dim3(512), 0, stream>>>(teaBf, Wt, bias, proj);
  else
    gemmFbK<<<dim3(64, NIMG), dim3(256), 0, stream>>>(teaQ, teaP, Wt, bias, proj);

  candK<<<dim3(2048), dim3(256), 0, stream>>>(stuQ, stuP, proj, accf);
  finalK<<<dim3(1), dim3(1), 0, stream>>>(accf, out);
}

// Round 6
// 622.539 us; speedup vs baseline: 4.7974x; 1.1029x over previous
//
#include <hip/hip_runtime.h>
#include <stdint.h>

#define B_IMG 64
#define NIMG 128
#define NS 576
#define NT 1024
#define DSZ 1024
#define DT 1152
#define TEMPR 0.02f

typedef float f32x4 __attribute__((ext_vector_type(4)));
typedef __bf16 bf16x8 __attribute__((ext_vector_type(8)));

// ---------- ws layout ----------
constexpr size_t OFF_PROJ = 0;                                 // bf16 proj [NIMG][NT][DSZ]
constexpr size_t SZ_PROJ = (size_t)NIMG * NT * DSZ * 2;
constexpr size_t OFF_WT = OFF_PROJ + SZ_PROJ;                  // bf16 W^T [DSZ][DT]
constexpr size_t SZ_WT = (size_t)DSZ * DT * 2;
constexpr size_t OFF_ACC = OFF_WT + SZ_WT;                     // 2 x f32 (contr, kd)
constexpr size_t WS_BASIC = OFF_ACC + 16;
constexpr size_t OFF_TEA = (WS_BASIC + 255) & ~(size_t)255;    // bf16 [NIMG][NT][DT]
constexpr size_t SZ_TEA = (size_t)NIMG * NT * DT * 2;
constexpr size_t WS_FULL = OFF_TEA + SZ_TEA;

// ---------- helpers ----------
__device__ __forceinline__ unsigned short f2bf(float f) {
  union { float f; uint32_t u; } c; c.f = f;
  uint32_t u = c.u;
  uint32_t r = u + 0x7FFFu + ((u >> 16) & 1u);
  return (unsigned short)(r >> 16);
}
__device__ __forceinline__ float bf2f(unsigned short b) {
  union { float f; uint32_t u; } c; c.u = ((uint32_t)b) << 16;
  return c.f;
}
__device__ __forceinline__ bf16x8 cvt8(float4 a, float4 b) {
  bf16x8 r;
  r[0] = (__bf16)a.x; r[1] = (__bf16)a.y; r[2] = (__bf16)a.z; r[3] = (__bf16)a.w;
  r[4] = (__bf16)b.x; r[5] = (__bf16)b.y; r[6] = (__bf16)b.z; r[7] = (__bf16)b.w;
  return r;
}
__device__ __forceinline__ void async16(unsigned short* lds, const unsigned short* g) {
  __builtin_amdgcn_global_load_lds(
      (const __attribute__((address_space(1))) unsigned int*)g,
      (__attribute__((address_space(3))) unsigned int*)lds, 16, 0, 0);
}

// ---------- small kernels ----------
__global__ void initAccK(float* accf) {
  if (threadIdx.x == 0) { accf[0] = 0.f; accf[1] = 0.f; }
}

__global__ __launch_bounds__(256) void cvtK(const float* __restrict__ in,
                                            unsigned short* __restrict__ out, int n8) {
  int i = blockIdx.x * 256 + threadIdx.x;
  if (i >= n8) return;
  const float4* p = (const float4*)in + (size_t)i * 2;
  *(bf16x8*)(out + (size_t)i * 8) = cvt8(p[0], p[1]);
}

// coalesced transpose W [DT][DSZ] f32 -> Wt [DSZ][DT] bf16
__global__ __launch_bounds__(256) void wtK(const float* __restrict__ W,
                                           unsigned short* __restrict__ Wt) {
  __shared__ float tile[32][33];
  int n0 = blockIdx.x * 32, k0 = blockIdx.y * 32;
  int tx = threadIdx.x & 31, ty = threadIdx.x >> 5;
  #pragma unroll
  for (int i = 0; i < 4; i++)
    tile[ty + i * 8][tx] = W[(size_t)(k0 + ty + i * 8) * DSZ + n0 + tx];
  __syncthreads();
  #pragma unroll
  for (int i = 0; i < 4; i++)
    Wt[(size_t)(n0 + ty + i * 8) * DT + k0 + tx] = f2bf(tile[tx][ty + i * 8]);
}

__global__ __launch_bounds__(64) void contrK(const float* __restrict__ q,
                                             const float* __restrict__ p, float* accf) {
  int i = blockIdx.x, l = threadIdx.x;
  const float4* qi = (const float4*)(q + (size_t)i * DSZ);
  const float4* pj = (const float4*)(p + (size_t)l * DSZ);
  float dot = 0.f;
  for (int k = 0; k < DSZ / 4; k++) {
    float4 a = qi[k], b = pj[k];
    dot += a.x * b.x + a.y * b.y + a.z * b.z + a.w * b.w;
  }
  float s = dot / TEMPR;
  float m = s;
  #pragma unroll
  for (int o = 32; o; o >>= 1) m = fmaxf(m, __shfl_xor(m, o));
  float e = expf(s - m);
  #pragma unroll
  for (int o = 32; o; o >>= 1) e += __shfl_xor(e, o);
  float lse = m + logf(e);
  float sii = __shfl(s, i);
  if (l == 0) atomicAdd(accf, sii - lse);
}

// ---------- 256x256 deep-pipelined projection GEMM (reg-double-buffered) ----------
// proj = teaBf @ Wt^T + b  (M=NT=1024, K=DT=1152, N=DSZ=1024)
// 8 waves (2Mx4N), wave tile 128x64; BK=32; 4 LDS bufs; frag regs double-buffered
// so ds_read(kt+1) and STAGE(kt+4) overlap MFMA(kt) within each wave.
__global__ __launch_bounds__(512, 2) void gemm256K(
    const unsigned short* __restrict__ teaBf, const unsigned short* __restrict__ Wt,
    const float* __restrict__ bias, unsigned short* __restrict__ proj) {
  // XCD-chunked bijective remap (2048 blocks % 8 == 0): each XCD gets 16 whole
  // images -> an image's 4 nt-tiles (A-panel reuse group) share one L2.
  const int bid = blockIdx.x;
  const int lb = (bid & 7) * 256 + (bid >> 3);
  const int b = lb >> 4;
  const int tile = lb & 15;
  const int mt = tile & 3;
  const int nt = tile >> 2;
  const int M0 = mt * 256, N0 = nt * 256;

  // [buf][A=0/B=1][256 rows x 32 k], slot-XOR swizzled rows (64B rows)
  __shared__ __align__(16) unsigned short lds[4][2][256 * 32];

  const int t = threadIdx.x;
  const int l = t & 63;
  const int w = t >> 6;
  const int wr = w >> 2;  // 0..1
  const int wc = w & 3;   // 0..3

  f32x4 acc[8][4];
  #pragma unroll
  for (int i = 0; i < 8; i++)
    #pragma unroll
    for (int j = 0; j < 4; j++) acc[i][j] = (f32x4){0.f, 0.f, 0.f, 0.f};

  const unsigned short* Abase = teaBf + (size_t)(b * NT + M0) * DT;
  const unsigned short* Bbase = Wt + (size_t)N0 * DT;
  const int row0 = t >> 2;
  const int row1 = (512 + t) >> 2;
  const int sl0 = (t & 3) ^ ((row0 >> 1) & 3);
  const int sl1 = (t & 3) ^ ((row1 >> 1) & 3);
  const unsigned short* gA0 = Abase + (size_t)row0 * DT + sl0 * 8;
  const unsigned short* gA1 = Abase + (size_t)row1 * DT + sl1 * 8;
  const unsigned short* gB0 = Bbase + (size_t)row0 * DT + sl0 * 8;
  const unsigned short* gB1 = Bbase + (size_t)row1 * DT + sl1 * 8;
  const int st0 = t * 8;
  const int st1 = (512 + t) * 8;

#define STAGE(TT) {                                      \
    int bf_ = (TT) & 3; int ko_ = (TT) * 32;             \
    async16(&lds[bf_][0][st0], gA0 + ko_);               \
    async16(&lds[bf_][0][st1], gA1 + ko_);               \
    async16(&lds[bf_][1][st0], gB0 + ko_);               \
    async16(&lds[bf_][1][st1], gB1 + ko_); }

  int aOff[8], bOff[4];
  #pragma unroll
  for (int mi = 0; mi < 8; mi++) {
    int m = wr * 128 + mi * 16 + (l & 15);
    aOff[mi] = m * 32 + (((l >> 4) ^ ((m >> 1) & 3)) * 8);
  }
  #pragma unroll
  for (int ni = 0; ni < 4; ni++) {
    int n = wc * 64 + ni * 16 + (l & 15);
    bOff[ni] = n * 32 + (((l >> 4) ^ ((n >> 1) & 3)) * 8);
  }

  bf16x8 afA[8], bfA[4], afB[8], bfB[4];

#define RD(SET, KT1) {                                                      \
    const unsigned short* aS = &lds[(KT1) & 3][0][0];                       \
    const unsigned short* bS = &lds[(KT1) & 3][1][0];                       \
    _Pragma("unroll")                                                       \
    for (int mi = 0; mi < 8; mi++) af##SET[mi] = *(const bf16x8*)&aS[aOff[mi]]; \
    _Pragma("unroll")                                                       \
    for (int ni = 0; ni < 4; ni++) bf##SET[ni] = *(const bf16x8*)&bS[bOff[ni]]; }

#define MM(SET) {                                                           \
    __builtin_amdgcn_s_setprio(1);                                          \
    _Pragma("unroll")                                                       \
    for (int mi = 0; mi < 8; mi++)                                          \
      _Pragma("unroll")                                                     \
      for (int ni = 0; ni < 4; ni++)                                        \
        acc[mi][ni] = __builtin_amdgcn_mfma_f32_16x16x32_bf16(              \
            af##SET[mi], bf##SET[ni], acc[mi][ni], 0, 0, 0);                \
    __builtin_amdgcn_s_setprio(0); }

#define K_ITER(KT, VMLIT, DO_STG, DO_READ, CUR, NXT) {                      \
    asm volatile("s_waitcnt lgkmcnt(0)" ::: "memory");                      \
    asm volatile("s_waitcnt vmcnt(" VMLIT ")" ::: "memory");                \
    __builtin_amdgcn_s_barrier();                                           \
    asm volatile("" ::: "memory");                                          \
    if (DO_STG) STAGE((KT) + 4);                                            \
    if (DO_READ) RD(NXT, (KT) + 1);                                         \
    MM(CUR); }

  // prologue: 4 K-tiles staged; pre-read R(0) into set A
  STAGE(0); STAGE(1); STAGE(2); STAGE(3);
  asm volatile("s_waitcnt vmcnt(12)" ::: "memory");
  __builtin_amdgcn_s_barrier();
  asm volatile("" ::: "memory");
  RD(A, 0);

  for (int kt = 0; kt < 32; kt += 2) {
    K_ITER(kt, "8", true, true, A, B);
    K_ITER(kt + 1, "8", true, true, B, A);
  }
  K_ITER(32, "8", false, true, A, B);
  K_ITER(33, "4", false, true, B, A);
  K_ITER(34, "0", false, true, A, B);
  K_ITER(35, "0", false, false, B, A);
#undef K_ITER
#undef MM
#undef RD
#undef STAGE

  // ---- coalesced epilogue through LDS (wave-private 16KB regions) ----
  __syncthreads();  // all staging/reads done; LDS reusable
  unsigned short* sc = &lds[0][0][0] + w * 8192;
  const int rbase = (l >> 4) * 4;
  const int cl = l & 15;
  #pragma unroll
  for (int ni = 0; ni < 4; ni++) {
    int col = N0 + wc * 64 + ni * 16 + cl;
    float bv = bias[col];
    #pragma unroll
    for (int mi = 0; mi < 8; mi++) {
      #pragma unroll
      for (int r = 0; r < 4; r++) {
        int row = mi * 16 + rbase + r;
        // XOR row-group into byte bits 5-6: write is bank-conflict-free
        int byteoff = row * 128 + ((ni * 32 + cl * 2) ^ (((row >> 2) & 3) << 5));
        *(unsigned short*)((char*)sc + byteoff) = f2bf(acc[mi][ni][r] + bv);
      }
    }
  }
  asm volatile("s_waitcnt lgkmcnt(0)" ::: "memory");
  #pragma unroll
  for (int p = 0; p < 16; p++) {
    int row = p * 8 + (l >> 3);
    int byteoff = row * 128 + (((l & 7) * 16) ^ (((row >> 2) & 3) << 5));
    bf16x8 v = *(const bf16x8*)((const char*)sc + byteoff);
    int grow = M0 + wr * 128 + row;
    int gcol = N0 + wc * 64 + (l & 7) * 8;
    *(bf16x8*)&proj[((size_t)b * NT + grow) * DSZ + gcol] = v;
  }
}

// ---------- fallback 128x128 GEMM (small-ws path, converts A in-kernel) ----------
__global__ __launch_bounds__(256) void gemmFbK(
    const float* __restrict__ teaQ, const float* __restrict__ teaP,
    const unsigned short* __restrict__ Wt, const float* __restrict__ bias,
    unsigned short* __restrict__ proj) {
  constexpr int K = DT;
  const int b = blockIdx.y;
  const int mt = blockIdx.x & 7;
  const int nt = blockIdx.x >> 3;
  const int M0 = mt * 128, N0 = nt * 128;

  __shared__ __align__(16) unsigned short As[128 * 32];
  __shared__ __align__(16) unsigned short Bs[128 * 32];

  const int t = threadIdx.x;
  const int l = t & 63;
  const int w = t >> 6;
  const int wr = w >> 1, wc = w & 1;

  f32x4 acc[4][4];
  #pragma unroll
  for (int i = 0; i < 4; i++)
    #pragma unroll
    for (int j = 0; j < 4; j++) acc[i][j] = (f32x4){0.f, 0.f, 0.f, 0.f};

  const float* Af32 = (b < B_IMG) ? teaQ + (size_t)b * NT * DT
                                  : teaP + (size_t)(b - B_IMG) * NT * DT;
  const int arowF = t >> 1;
  const int chunkF = t & 1;
  const int swF = (arowF >> 1) & 3;
  const float* aptrF = Af32 + (size_t)(M0 + arowF) * K + chunkF * 16;

  int prow = (t * 16) >> 6;
  int psl = ((t * 16 >> 4) & 3) ^ ((prow >> 1) & 3);
  const unsigned short* gB0 = Wt + (size_t)(N0 + prow) * K + psl * 8;
  int prow1 = ((t + 256) * 16) >> 6;
  int psl1 = (((t + 256) * 16 >> 4) & 3) ^ ((prow1 >> 1) & 3);
  const unsigned short* gB1 = Wt + (size_t)(N0 + prow1) * K + psl1 * 8;
  unsigned short* ldsB0 = Bs + t * 8;
  unsigned short* ldsB1 = Bs + (t + 256) * 8;

  for (int kt = 0; kt < K; kt += 32) {
    const float4* a4 = (const float4*)(aptrF + kt);
    bf16x8 v0 = cvt8(a4[0], a4[1]);
    bf16x8 v1 = cvt8(a4[2], a4[3]);
    *(bf16x8*)&As[arowF * 32 + ((2 * chunkF + 0) ^ swF) * 8] = v0;
    *(bf16x8*)&As[arowF * 32 + ((2 * chunkF + 1) ^ swF) * 8] = v1;
    async16(ldsB0, gB0 + kt);
    async16(ldsB1, gB1 + kt);
    __syncthreads();

    bf16x8 af[4], bfv[4];
    #pragma unroll
    for (int mi = 0; mi < 4; mi++) {
      int m = wr * 64 + mi * 16 + (l & 15);
      af[mi] = *(const bf16x8*)&As[m * 32 + (((l >> 4) ^ ((m >> 1) & 3)) * 8)];
    }
    #pragma unroll
    for (int ni = 0; ni < 4; ni++) {
      int n = wc * 64 + ni * 16 + (l & 15);
      bfv[ni] = *(const bf16x8*)&Bs[n * 32 + (((l >> 4) ^ ((n >> 1) & 3)) * 8)];
    }
    #pragma unroll
    for (int mi = 0; mi < 4; mi++)
      #pragma unroll
      for (int ni = 0; ni < 4; ni++)
        acc[mi][ni] =
            __builtin_amdgcn_mfma_f32_16x16x32_bf16(af[mi], bfv[ni], acc[mi][ni], 0, 0, 0);
    __syncthreads();
  }

  const int rbase = (l >> 4) * 4;
  const int cl = l & 15;
  #pragma unroll
  for (int ni = 0; ni < 4; ni++) {
    int col = N0 + wc * 64 + ni * 16 + cl;
    float bv = bias[col];
    #pragma unroll
    for (int mi = 0; mi < 4; mi++) {
      int row = M0 + wr * 64 + mi * 16 + rbase;
      #pragma unroll
      for (int r = 0; r < 4; r++)
        proj[((size_t)b * NT + row + r) * DSZ + col] = f2bf(acc[mi][ni][r] + bv);
    }
  }
}

// ---------- candidate-match + MSE in one pass ----------
__global__ __launch_bounds__(256) void candK(const float* __restrict__ stuQ,
                                             const float* __restrict__ stuP,
                                             const unsigned short* __restrict__ proj,
                                             float* accf) {
  const int l = threadIdx.x & 63;
  const int w = threadIdx.x >> 6;
  const int gw = blockIdx.x * 4 + w;  // 8192 waves x 9 rows = 73728 rows
  float acc = 0.f;
  #pragma unroll 1
  for (int k = 0; k < 9; k++) {
    int rr = gw * 9 + k;
    int b = rr / NS, i = rr - b * NS;
    const float* srow = (b < B_IMG) ? stuQ + ((size_t)b * NS + i) * DSZ
                                    : stuP + ((size_t)(b - B_IMG) * NS + i) * DSZ;
    const float4* sp = (const float4*)(srow + l * 16);
    float4 s0 = sp[0], s1 = sp[1], s2 = sp[2], s3 = sp[3];

    int iy = i / 24, ix = i - iy * 24;
    int ry = iy % 3, rx = ix % 3;
    int jy0, jy1, jx0, jx1;
    if (ry == 0)      { jy0 = jy1 = (4 * iy) / 3; }
    else if (ry == 1) { jy0 = (4 * iy - 1) / 3; jy1 = (4 * iy + 2) / 3; }
    else              { jy0 = jy1 = (4 * iy + 1) / 3; }
    if (rx == 0)      { jx0 = jx1 = (4 * ix) / 3; }
    else if (rx == 1) { jx0 = (4 * ix - 1) / 3; jx1 = (4 * ix + 2) / 3; }
    else              { jx0 = jx1 = (4 * ix + 1) / 3; }

    const unsigned short* pbase = proj + (size_t)b * NT * DSZ;
    float best = __builtin_inff();
    #pragma unroll
    for (int cy = 0; cy < 2; cy++) {
      int jy = cy ? jy1 : jy0;
      if (cy && jy1 == jy0) continue;
      #pragma unroll
      for (int cx = 0; cx < 2; cx++) {
        int jx = cx ? jx1 : jx0;
        if (cx && jx1 == jx0) continue;
        int col = jy * 32 + jx;
        const uint4* pr = (const uint4*)(pbase + (size_t)col * DSZ + l * 16);
        uint4 p0 = pr[0], p1 = pr[1];
        float sq = 0.f;
        {
          float d;
          d = s0.x - bf2f((unsigned short)(p0.x & 0xFFFF)); sq += d * d;
          d = s0.y - bf2f((unsigned short)(p0.x >> 16));    sq += d * d;
          d = s0.z - bf2f((unsigned short)(p0.y & 0xFFFF)); sq += d * d;
          d = s0.w - bf2f((unsigned short)(p0.y >> 16));    sq += d * d;
          d = s1.x - bf2f((unsigned short)(p0.z & 0xFFFF)); sq += d * d;
          d = s1.y - bf2f((unsigned short)(p0.z >> 16));    sq += d * d;
          d = s1.z - bf2f((unsigned short)(p0.w & 0xFFFF)); sq += d * d;
          d = s1.w - bf2f((unsigned short)(p0.w >> 16));    sq += d * d;
          d = s2.x - bf2f((unsigned short)(p1.x & 0xFFFF)); sq += d * d;
          d = s2.y - bf2f((unsigned short)(p1.x >> 16));    sq += d * d;
          d = s2.z - bf2f((unsigned short)(p1.y & 0xFFFF)); sq += d * d;
          d = s2.w - bf2f((unsigned short)(p1.y >> 16));    sq += d * d;
          d = s3.x - bf2f((unsigned short)(p1.z & 0xFFFF)); sq += d * d;
          d = s3.y - bf2f((unsigned short)(p1.z >> 16));    sq += d * d;
          d = s3.z - bf2f((unsigned short)(p1.w & 0xFFFF)); sq += d * d;
          d = s3.w - bf2f((unsigned short)(p1.w >> 16));    sq += d * d;
        }
        #pragma unroll
        for (int o = 32; o; o >>= 1) sq += __shfl_xor(sq, o);
        if (sq < best) best = sq;  // increasing col order => first-occurrence ties
      }
    }
    acc += best;
  }
  __shared__ float red[4];
  if (l == 0) red[w] = acc;
  __syncthreads();
  if (threadIdx.x == 0)
    atomicAdd(accf + 1, red[0] + red[1] + red[2] + red[3]);
}

__global__ void finalK(const float* accf, float* out) {
  float contr = -accf[0] / (float)B_IMG;
  float kd = (accf[1] / (float)(NS * DSZ)) / (2.f * B_IMG + 1e-8f);
  out[0] = contr + kd;
}

extern "C" void kernel_launch(void* const* d_in, const int* in_sizes, int n_in,
                              void* d_out, int out_size, void* d_ws, size_t ws_size,
                              hipStream_t stream) {
  const float* stuQ = (const float*)d_in[0];
  const float* teaQ = (const float*)d_in[1];
  const float* stuP = (const float*)d_in[2];
  const float* teaP = (const float*)d_in[3];
  const float* qreps = (const float*)d_in[4];
  const float* preps = (const float*)d_in[5];
  const float* W = (const float*)d_in[6];
  const float* bias = (const float*)d_in[7];

  if (ws_size < WS_BASIC) return;
  const bool full = ws_size >= WS_FULL;

  char* ws = (char*)d_ws;
  unsigned short* proj = (unsigned short*)(ws + OFF_PROJ);
  unsigned short* Wt = (unsigned short*)(ws + OFF_WT);
  float* accf = (float*)(ws + OFF_ACC);
  unsigned short* teaBf = (unsigned short*)(ws + OFF_TEA);
  float* out = (float*)d_out;

  initAccK<<<dim3(1), dim3(64), 0, stream>>>(accf);
  wtK<<<dim3(DSZ / 32, DT / 32), dim3(256), 0, stream>>>(W, Wt);
  if (full) {
    const int nTea8 = B_IMG * NT * DT / 8;
    cvtK<<<dim3(nTea8 / 256), dim3(256), 0, stream>>>(teaQ, teaBf, nTea8);
    cvtK<<<dim3(nTea8 / 256), dim3(256), 0, stream>>>(
        teaP, teaBf + (size_t)B_IMG * NT * DT, nTea8);
  }
  contrK<<<dim3(B_IMG), dim3(64), 0, stream>>>(qreps, preps, accf);

  if (full)
    gemm256K<<<dim3(2048), dim3(512), 0, stream>>>(teaBf, Wt, bias, proj);
  else
    gemmFbK<<<dim3(64, NIMG), dim3(256), 0, stream>>>(teaQ, teaP, Wt, bias, proj);

  candK<<<dim3(2048), dim3(256), 0, stream>>>(stuQ, stuP, proj, accf);
  finalK<<<dim3(1), dim3(1), 0, stream>>>(accf, out);
}